// Round 4
// baseline (7535.835 us; speedup 1.0000x reference)
//
#include <hip/hip_runtime.h>
#include <cstdint>
#include <cstddef>

typedef unsigned short u16;
typedef __bf16 bf16x8 __attribute__((ext_vector_type(8)));
typedef float f32x4 __attribute__((ext_vector_type(4)));
typedef unsigned short u16x8 __attribute__((ext_vector_type(8)));

#define NB   256
#define MAXN 128
#define MAXE 256
#define MAXC 64
#define HD   256
#define NLAYER 4
#define PN 131072
#define PE 98304
#define QE 131072
#define QC 65536
#define MN (NB*MAXN)   /* 32768 node rows  */
#define ME (NB*MAXE)   /* 65536 edge rows  */
#define MC (NB*MAXC)   /* 16384 cell rows  */

__device__ __forceinline__ float bf2f(u16 u){
  union{unsigned int i; float f;} x; x.i = ((unsigned int)u) << 16; return x.f;
}
__device__ __forceinline__ u16 f2bf(float f){
  union{float f; unsigned int i;} x; x.f = f;
  unsigned int r = x.i + 0x7fffu + ((x.i >> 16) & 1u);
  return (u16)(r >> 16);
}
__device__ __forceinline__ void atomAddF(float* p, float v){
  (void)__hip_atomic_fetch_add(p, v, __ATOMIC_RELAXED, __HIP_MEMORY_SCOPE_AGENT);
}
__device__ __forceinline__ f32x4 MFMA(bf16x8 a, bf16x8 b, f32x4 c){
  return __builtin_amdgcn_mfma_f32_16x16x32_bf16(a, b, c, 0, 0, 0);
}

// ---------------- dtype sniff: bf16 buffers -> ~64/64 sane exponents; f32 -> ~34/64
__global__ void detect_dtype(const u16* __restrict__ x, int* __restrict__ flag){
  if(threadIdx.x == 0 && blockIdx.x == 0){
    int cnt = 0;
    for(int i = 0; i < 64; i++){
      int e = (x[i] >> 7) & 0xFF;
      if(e >= 118 && e <= 136) cnt++;
    }
    *flag = (cnt >= 50) ? 1 : 0;   // 1 = bf16, 0 = f32
  }
}

// ---------------- dtype-aware convert to bf16 (copy if already bf16)
__global__ __launch_bounds__(256) void conv_bf(const void* __restrict__ src, u16* __restrict__ dst,
                                               long n, const int* __restrict__ flag){
  long i = ((long)blockIdx.x * 256 + threadIdx.x) * 8;
  if(i >= n) return;
  const int isbf = *flag;
  if(i + 8 <= n){
    if(isbf){
      *reinterpret_cast<u16x8*>(dst + i) = *reinterpret_cast<const u16x8*>((const u16*)src + i);
    }else{
      const float* s = (const float*)src + i;
      float4 a = *reinterpret_cast<const float4*>(s);
      float4 b = *reinterpret_cast<const float4*>(s + 4);
      u16x8 o;
      o[0]=f2bf(a.x); o[1]=f2bf(a.y); o[2]=f2bf(a.z); o[3]=f2bf(a.w);
      o[4]=f2bf(b.x); o[5]=f2bf(b.y); o[6]=f2bf(b.z); o[7]=f2bf(b.w);
      *reinterpret_cast<u16x8*>(dst + i) = o;
    }
  }else{
    for(long e = i; e < n; e++)
      dst[e] = isbf ? ((const u16*)src)[e] : f2bf(((const float*)src)[e]);
  }
}

// ---------------- zero fill (workspace is poisoned 0xAA before every launch)
__global__ __launch_bounds__(256) void zero_f4(float* __restrict__ p, long n4){
  long i = (long)blockIdx.x * blockDim.x + threadIdx.x;
  if(i >= n4) return;
  float4 z = {0.f, 0.f, 0.f, 0.f};
  *reinterpret_cast<float4*>(p + i * 4) = z;
}

// ---------------- dtype-aware weight transpose: src [K=256,N=256] -> bf16 dst [n*256+k]
__global__ void wt_transpose(const void* __restrict__ src, u16* __restrict__ dst,
                             const int* __restrict__ flag){
  __shared__ u16 t[16][17];
  int m = blockIdx.z;
  int n0 = blockIdx.x * 16, k0 = blockIdx.y * 16;
  size_t sidx = (size_t)m * 65536 + (size_t)(k0 + threadIdx.y) * 256 + n0 + threadIdx.x;
  u16 v = (*flag) ? ((const u16*)src)[sidx] : f2bf(((const float*)src)[sidx]);
  t[threadIdx.y][threadIdx.x] = v;
  __syncthreads();
  dst[(size_t)m * 65536 + (size_t)(n0 + threadIdx.y) * 256 + (k0 + threadIdx.x)] =
      t[threadIdx.x][threadIdx.y];
}

// ---------------- dedup boundary incidences (.set(1.0) semantics: idempotent)
__global__ void dedup_kernel(const int* __restrict__ bb, const int* __restrict__ bi,
                             const int* __restrict__ bj, unsigned int* __restrict__ mask,
                             unsigned char* __restrict__ valid, int Q, int maxI, int maxJ){
  int q = blockIdx.x * blockDim.x + threadIdx.x;
  if(q >= Q) return;
  int s = (bb[q] * maxI + bi[q]) * maxJ + bj[q];
  unsigned int bit = 1u << (s & 31);
  unsigned int old = atomicOr(&mask[s >> 5], bit);
  valid[q] = (old & bit) ? 0 : 1;
}

// ---------------- bf16 MFMA GEMM, 1-D grid over rows (rows % 64 == 0), N=K=256.
// MODE 0: C = A@W.  MODE 1: C = A@W + C (C != A).
// MODE 2: C = relu(A@W + ACC + bias), C may alias A (A preloaded + barrier).
template<int MODE>
__global__ __launch_bounds__(256) void gemm_k(const u16* A,
    const u16* __restrict__ WT, u16* C,
    const float* __restrict__ ACC, const u16* __restrict__ bias){
  const int lane = threadIdx.x & 63;
  const int wv = threadIdx.x >> 6;
  const int wm = wv >> 1, wn = wv & 1;
  const int r = lane & 15, q = lane >> 4;
  const int mbase = blockIdx.x * 64 + wm * 32;
  bf16x8 af[2][8];
  const u16* abase = A + (size_t)(mbase + r) * 256 + q * 8;
#pragma unroll
  for(int t = 0; t < 8; t++){
    af[0][t] = *reinterpret_cast<const bf16x8*>(abase + t * 32);
    af[1][t] = *reinterpret_cast<const bf16x8*>(abase + 16 * 256 + t * 32);
  }
  if(MODE == 2) __syncthreads();
  const int crow0 = mbase + q * 4;
#pragma unroll
  for(int nt = 0; nt < 4; nt++){
    const int ncol = wn * 128 + nt * 32;
    const u16* bbase = WT + (size_t)(ncol + r) * 256 + q * 8;
    f32x4 ac00 = {0.f,0.f,0.f,0.f};
    f32x4 ac01 = ac00, ac10 = ac00, ac11 = ac00;
#pragma unroll
    for(int t = 0; t < 8; t++){
      bf16x8 b0 = *reinterpret_cast<const bf16x8*>(bbase + t * 32);
      bf16x8 b1 = *reinterpret_cast<const bf16x8*>(bbase + 16 * 256 + t * 32);
      ac00 = MFMA(af[0][t], b0, ac00);
      ac01 = MFMA(af[0][t], b1, ac01);
      ac10 = MFMA(af[1][t], b0, ac10);
      ac11 = MFMA(af[1][t], b1, ac11);
    }
#pragma unroll
    for(int i = 0; i < 4; i++){
      float v[4] = {ac00[i], ac01[i], ac10[i], ac11[i]};
      const int rr[4] = {crow0 + i, crow0 + i, crow0 + 16 + i, crow0 + 16 + i};
      const int cc[4] = {ncol + r, ncol + 16 + r, ncol + r, ncol + 16 + r};
#pragma unroll
      for(int s = 0; s < 4; s++){
        const size_t idx = (size_t)rr[s] * 256 + cc[s];
        float x = v[s];
        if(MODE == 1) x += bf2f(C[idx]);
        if(MODE == 2) x = fmaxf(x + ACC[idx] + bf2f(bias[cc[s]]), 0.f);
        C[idx] = f2bf(x);
      }
    }
  }
}

// ---------------- up messages: ACC[i-lo] += relu(Y[j] + Z[a]); wave per pair
__global__ __launch_bounds__(256) void up_scatter(const u16* __restrict__ Y, const u16* __restrict__ Z,
    const int* __restrict__ pb, const int* __restrict__ pi, const int* __restrict__ pj,
    const int* __restrict__ pa, float* __restrict__ acc, int P, int maxI, int maxA,
    int rowLo, int rowHi){
  int p = blockIdx.x * 4 + (threadIdx.x >> 6);
  if(p >= P) return;
  int b = pb[p];
  int ir = b * maxI + pi[p];
  if(ir < rowLo || ir >= rowHi) return;
  int lane = threadIdx.x & 63;
  int jr = b * maxI + pj[p];
  int ar = b * maxA + pa[p];
  int c = lane * 4;
  const ushort4 y = *reinterpret_cast<const ushort4*>(Y + (size_t)jr * 256 + c);
  const ushort4 z = *reinterpret_cast<const ushort4*>(Z + (size_t)ar * 256 + c);
  float* d = acc + (size_t)(ir - rowLo) * 256 + c;
  atomAddF(d + 0, fmaxf(bf2f(y.x) + bf2f(z.x), 0.f));
  atomAddF(d + 1, fmaxf(bf2f(y.y) + bf2f(z.y), 0.f));
  atomAddF(d + 2, fmaxf(bf2f(y.z) + bf2f(z.z), 0.f));
  atomAddF(d + 3, fmaxf(bf2f(y.w) + bf2f(z.w), 0.f));
}

// ---------------- boundary messages: ACC[i-lo] += SRC[j] for dedup'd (b,i,j)
__global__ __launch_bounds__(256) void bd_scatter(const u16* __restrict__ SRC,
    const int* __restrict__ bb, const int* __restrict__ bi, const int* __restrict__ bj,
    const unsigned char* __restrict__ valid, float* __restrict__ acc, int Q,
    int maxI, int maxJ, int rowLo, int rowHi){
  int q = blockIdx.x * 4 + (threadIdx.x >> 6);
  if(q >= Q) return;
  if(!valid[q]) return;
  int b = bb[q];
  int dr = b * maxI + bi[q];
  if(dr < rowLo || dr >= rowHi) return;
  int lane = threadIdx.x & 63;
  int sr = b * maxJ + bj[q];
  int c = lane * 4;
  const ushort4 x = *reinterpret_cast<const ushort4*>(SRC + (size_t)sr * 256 + c);
  float* d = acc + (size_t)(dr - rowLo) * 256 + c;
  atomAddF(d + 0, bf2f(x.x));
  atomAddF(d + 1, bf2f(x.y));
  atomAddF(d + 2, bf2f(x.z));
  atomAddF(d + 3, bf2f(x.w));
}

// ---------------- pooled[b,h] += sum_r sigmoid(G+bp)[r,h] * X[r,h]
__global__ __launch_bounds__(256) void pool_reduce(const u16* __restrict__ G, const u16* __restrict__ bpv,
    const u16* __restrict__ X, float* __restrict__ pooled, int maxR, int rowsPerBlk){
  int b = blockIdx.x, h = threadIdx.x;
  int r0 = blockIdx.y * rowsPerBlk;
  float bias = bf2f(bpv[h]);
  float acc = 0.f;
  for(int r = r0; r < r0 + rowsPerBlk; r++){
    size_t o = ((size_t)b * maxR + r) * 256 + h;
    float t = bf2f(G[o]) + bias;
    float w = 1.f / (1.f + __expf(-t));
    acc += w * bf2f(X[o]);
  }
  atomicAdd(&pooled[b * 256 + h], acc);
}

// ---------------- h[b,o] = sum_i relu(pooled_i[b,:] @ W1[i] + b1[i])
__global__ __launch_bounds__(512) void readout1(const float* __restrict__ pooled, const u16* __restrict__ W1,
                                                const u16* __restrict__ b1, float* __restrict__ hbuf){
  __shared__ float p[3][256];
  int b = blockIdx.x, o = threadIdx.x;
  if(o < 256){
    p[0][o] = pooled[(size_t)b * 256 + o];
    p[1][o] = pooled[(size_t)NB * 256 + (size_t)b * 256 + o];
    p[2][o] = pooled[(size_t)2 * NB * 256 + (size_t)b * 256 + o];
  }
  __syncthreads();
  float s = 0.f;
#pragma unroll
  for(int i = 0; i < 3; i++){
    float a = bf2f(b1[i * 512 + o]);
    for(int k = 0; k < 256; k++) a += p[i][k] * bf2f(W1[(size_t)(i * 256 + k) * 512 + o]);
    s += fmaxf(a, 0.f);
  }
  hbuf[(size_t)b * 512 + o] = s;
}

// ---------------- out = h @ W2 + b2  (dtype-matched store)
__global__ __launch_bounds__(64) void readout2(const float* __restrict__ hbuf, const u16* __restrict__ W2,
                                               const u16* __restrict__ b2, void* __restrict__ out,
                                               const int* __restrict__ flag){
  int b = blockIdx.x, o = threadIdx.x;
  if(o >= 10) return;
  float a = bf2f(b2[o]);
  for(int k = 0; k < 512; k++) a += hbuf[(size_t)b * 512 + k] * bf2f(W2[k * 10 + o]);
  if(*flag) ((u16*)out)[b * 10 + o] = f2bf(a);
  else      ((float*)out)[b * 10 + o] = a;
}

extern "C" void kernel_launch(void* const* d_in, const int* in_sizes, int n_in,
                              void* d_out, int out_size, void* d_ws, size_t ws_size,
                              hipStream_t stream){
  const void* x_n = d_in[0];
  const void* x_e = d_in[1];
  const void* x_c = d_in[2];
  const int* n_up_b = (const int*)d_in[3];
  const int* n_up_i = (const int*)d_in[4];
  const int* n_up_j = (const int*)d_in[5];
  const int* n_up_e = (const int*)d_in[6];
  const int* e_up_b = (const int*)d_in[7];
  const int* e_up_i = (const int*)d_in[8];
  const int* e_up_j = (const int*)d_in[9];
  const int* e_up_c = (const int*)d_in[10];
  const int* eb_b = (const int*)d_in[11];
  const int* eb_i = (const int*)d_in[12];
  const int* eb_j = (const int*)d_in[13];
  const int* cb_b = (const int*)d_in[14];
  const int* cb_i = (const int*)d_in[15];
  const int* cb_j = (const int*)d_in[16];

  // ---- workspace carve-up (matches round-3's proven-writable ~160 MiB footprint)
  char* base = (char*)d_ws; size_t off = 0;
  auto alloc = [&](size_t n)->char*{ char* p = base + off; off = (off + n + 255) & ~(size_t)255; return p; };
  u16* xn = (u16*)alloc((size_t)MN * HD * 2);
  u16* xe = (u16*)alloc((size_t)ME * HD * 2);
  u16* xc = (u16*)alloc((size_t)MC * HD * 2);
  u16* BIG1 = (u16*)alloc((size_t)ME * HD * 2);      // Ze/BDe/Ye/G staging
  u16* SMa  = (u16*)alloc((size_t)MN * HD * 2);      // Yn then Zc; pool: ref scratch lo
  u16* SMb  = (u16*)alloc((size_t)MN * HD * 2);      // BDn;        pool: ref scratch hi
  float* ACC = (float*)alloc((size_t)MN * HD * 4);
  u16* wt = (u16*)alloc((size_t)38 * 65536 * 2);
  unsigned int* mask_e = (unsigned int*)alloc((size_t)NB * MAXE * MAXN / 8);  // 1 MiB, dead after dedup
  unsigned int* mask_c = (unsigned int*)alloc((size_t)NB * MAXC * MAXE / 8);
  unsigned char* valid_e = (unsigned char*)alloc(QE);
  unsigned char* valid_c = (unsigned char*)alloc(QC);
  float* pooled = (float*)alloc((size_t)3 * NB * HD * 4);
  float* hbuf   = (float*)alloc((size_t)NB * 512 * 4);
  int* flag     = (int*)alloc(256);

  u16* wtSelf = wt;
  u16* wtUpx  = wt + (size_t)12 * 65536;
  u16* wtUpa  = wt + (size_t)20 * 65536;
  u16* wtB    = wt + (size_t)28 * 65536;
  u16* wtP    = wt + (size_t)36 * 65536;
  u16* wtPref = wt + (size_t)37 * 65536;

  // small converted params live in mask_e's 1 MiB (dead after dedup): 806 KB used
  u16* W1c = (u16*)mask_e;            // 393216
  u16* b1c = W1c + 393216;            // 1536
  u16* W2c = b1c + 1536;              // 5120
  u16* b2c = W2c + 5120;              // 10 (+pad)
  u16* bsc = b2c + 16;                // 3072 (bself)
  u16* bpc = bsc + 3072;              // 256  (bp)

  auto convN = [&](const void* s, u16* d, long n){
    long blk = (n + 8*256 - 1) / (8*256);
    conv_bf<<<(int)blk, 256, 0, stream>>>(s, d, n, flag);
  };

  // ---- prologue: sniff dtype, dedup (uses mask_e), then convert params over mask_e
  detect_dtype<<<1, 64, 0, stream>>>((const u16*)x_n, flag);
  {
    long nm_e = (long)NB * MAXE * MAXN / 32 / 4;
    long nm_c = (long)NB * MAXC * MAXE / 32 / 4;
    zero_f4<<<(int)((nm_e + 255)/256), 256, 0, stream>>>((float*)mask_e, nm_e);
    zero_f4<<<(int)((nm_c + 255)/256), 256, 0, stream>>>((float*)mask_c, nm_c);
  }
  dedup_kernel<<<QE/256, 256, 0, stream>>>(eb_b, eb_i, eb_j, mask_e, valid_e, QE, MAXE, MAXN);
  dedup_kernel<<<QC/256, 256, 0, stream>>>(cb_b, cb_i, cb_j, mask_c, valid_c, QC, MAXC, MAXE);

  wt_transpose<<<dim3(16,16,12), dim3(16,16), 0, stream>>>(d_in[17], wtSelf, flag);
  wt_transpose<<<dim3(16,16,8),  dim3(16,16), 0, stream>>>(d_in[19], wtUpx,  flag);
  wt_transpose<<<dim3(16,16,8),  dim3(16,16), 0, stream>>>(d_in[20], wtUpa,  flag);
  wt_transpose<<<dim3(16,16,8),  dim3(16,16), 0, stream>>>(d_in[21], wtB,    flag);
  wt_transpose<<<dim3(16,16,1),  dim3(16,16), 0, stream>>>(d_in[22], wtP,    flag);
  wt_transpose<<<dim3(16,16,1),  dim3(16,16), 0, stream>>>(d_in[23], wtPref, flag);
  convN(x_n, xn, (long)MN * HD);
  convN(x_e, xe, (long)ME * HD);
  convN(x_c, xc, (long)MC * HD);
  convN(d_in[18], bsc, 3072);      // bself
  convN(d_in[24], bpc, 256);       // bp
  convN(d_in[25], W1c, 393216);    // W1
  convN(d_in[26], b1c, 1536);      // b1
  convN(d_in[27], W2c, 5120);      // W2
  convN(d_in[28], b2c, 10);        // b2

  const long accN4 = (long)MN * HD / 4;
  const long accC4 = (long)MC * HD / 4;

  // ---- layers (nodes -> cells -> edges in 2 halves)
  for(int l = 0; l < NLAYER; l++){
    const u16* Wupx0 = wtUpx + (size_t)(l*2+0) * 65536;
    const u16* Wupx1 = wtUpx + (size_t)(l*2+1) * 65536;
    const u16* Wupa0 = wtUpa + (size_t)(l*2+0) * 65536;
    const u16* Wupa1 = wtUpa + (size_t)(l*2+1) * 65536;
    const u16* Wb0   = wtB   + (size_t)(l*2+0) * 65536;
    const u16* Wb1   = wtB   + (size_t)(l*2+1) * 65536;
    const u16* Ws0   = wtSelf + (size_t)(l*3+0) * 65536;
    const u16* Ws1   = wtSelf + (size_t)(l*3+1) * 65536;
    const u16* Ws2   = wtSelf + (size_t)(l*3+2) * 65536;
    const u16* bs0 = bsc + (size_t)(l*3+0) * HD;
    const u16* bs1 = bsc + (size_t)(l*3+1) * HD;
    const u16* bs2 = bsc + (size_t)(l*3+2) * HD;

    // nodes
    gemm_k<0><<<MN/64, 256, 0, stream>>>(xn, Wupx0, SMa, nullptr, nullptr);
    gemm_k<0><<<ME/64, 256, 0, stream>>>(xe, Wupa0, BIG1, nullptr, nullptr);
    zero_f4<<<(int)(accN4/256), 256, 0, stream>>>(ACC, accN4);
    up_scatter<<<PN/4, 256, 0, stream>>>(SMa, BIG1, n_up_b, n_up_i, n_up_j, n_up_e,
                                         ACC, PN, MAXN, MAXE, 0, MN);
    gemm_k<0><<<MN/64, 256, 0, stream>>>(xn, Wb0, SMb, nullptr, nullptr);      // BDn (held)
    gemm_k<2><<<MN/64, 256, 0, stream>>>(xn, Ws0, xn, ACC, bs0);

    // cells
    gemm_k<0><<<MC/64, 256, 0, stream>>>(xc, Wupa1, SMa, nullptr, nullptr);    // Zc (held)
    gemm_k<0><<<ME/64, 256, 0, stream>>>(xe, Wb1, BIG1, nullptr, nullptr);     // BDe
    zero_f4<<<(int)(accC4/256), 256, 0, stream>>>(ACC, accC4);
    bd_scatter<<<QC/4, 256, 0, stream>>>(BIG1, cb_b, cb_i, cb_j, valid_c,
                                         ACC, QC, MAXC, MAXE, 0, MC);
    gemm_k<2><<<MC/64, 256, 0, stream>>>(xc, Ws2, xc, ACC, bs2);

    // edges
    gemm_k<0><<<ME/64, 256, 0, stream>>>(xe, Wupx1, BIG1, nullptr, nullptr);   // Ye (old xe)
    for(int h = 0; h < 2; h++){
      int lo = h * (ME/2), hi = lo + ME/2;
      zero_f4<<<(int)(accN4/256), 256, 0, stream>>>(ACC, accN4);
      up_scatter<<<PE/4, 256, 0, stream>>>(BIG1, SMa, e_up_b, e_up_i, e_up_j, e_up_c,
                                           ACC, PE, MAXE, MAXC, lo, hi);
      bd_scatter<<<QE/4, 256, 0, stream>>>(SMb, eb_b, eb_i, eb_j, valid_e,
                                           ACC, QE, MAXE, MAXN, lo, hi);
      gemm_k<2><<<(ME/2)/64, 256, 0, stream>>>(xe + (size_t)lo * HD, Ws1,
                                               xe + (size_t)lo * HD, ACC, bs1);
    }
  }

  // ---- gated pooling; refs re-converted from pristine d_in into SMa+SMb (32 MiB contiguous)
  u16* REF = SMa;
  {
    long np4 = (long)3 * NB * HD / 4;
    zero_f4<<<(int)((np4 + 255)/256), 256, 0, stream>>>(pooled, np4);
  }
  gemm_k<0><<<MN/64, 256, 0, stream>>>(xn, wtP, BIG1, nullptr, nullptr);
  convN(x_n, REF, (long)MN * HD);
  gemm_k<1><<<MN/64, 256, 0, stream>>>(REF, wtPref, BIG1, nullptr, nullptr);
  pool_reduce<<<dim3(NB,2), 256, 0, stream>>>(BIG1, bpc, xn, pooled, MAXN, MAXN/2);

  gemm_k<0><<<ME/64, 256, 0, stream>>>(xe, wtP, BIG1, nullptr, nullptr);
  convN(x_e, REF, (long)ME * HD);
  gemm_k<1><<<ME/64, 256, 0, stream>>>(REF, wtPref, BIG1, nullptr, nullptr);
  pool_reduce<<<dim3(NB,4), 256, 0, stream>>>(BIG1, bpc, xe, pooled + (size_t)NB*HD, MAXE, MAXE/4);

  gemm_k<0><<<MC/64, 256, 0, stream>>>(xc, wtP, BIG1, nullptr, nullptr);
  convN(x_c, REF, (long)MC * HD);
  gemm_k<1><<<MC/64, 256, 0, stream>>>(REF, wtPref, BIG1, nullptr, nullptr);
  pool_reduce<<<dim3(NB,1), 256, 0, stream>>>(BIG1, bpc, xc, pooled + (size_t)2*NB*HD, MAXC, MAXC);

  // ---- readout
  readout1<<<NB, 512, 0, stream>>>(pooled, W1c, b1c, hbuf);
  readout2<<<NB, 64, 0, stream>>>(hbuf, W2c, b2c, d_out, flag);
}

// Round 5
// 2282.336 us; speedup vs baseline: 3.3018x; 3.3018x over previous
//
#include <hip/hip_runtime.h>
#include <cstdint>
#include <cstddef>

typedef unsigned short u16;
typedef __bf16 bf16x8 __attribute__((ext_vector_type(8)));
typedef float f32x4 __attribute__((ext_vector_type(4)));
typedef unsigned short u16x8 __attribute__((ext_vector_type(8)));

#define NB   256
#define MAXN 128
#define MAXE 256
#define MAXC 64
#define HD   256
#define NLAYER 4
#define PN 131072
#define PE 98304
#define QE 131072
#define QC 65536
#define MN (NB*MAXN)   /* 32768 node rows  */
#define ME (NB*MAXE)   /* 65536 edge rows  */
#define MC (NB*MAXC)   /* 16384 cell rows  */

// CSR segment bases in the concatenated histogram/offset arrays
#define SEG_N  0
#define SEG_E  (MN)
#define SEG_EB (MN + ME)
#define SEG_CB (MN + 2*ME)
#define HTOT   (MN + 2*ME + MC)      /* 229376, divisible by 1024 */
#define UPTOT  (PN + PE)             /* csrBd global-index base   */

__device__ __forceinline__ float bf2f(u16 u){
  union{unsigned int i; float f;} x; x.i = ((unsigned int)u) << 16; return x.f;
}
__device__ __forceinline__ u16 f2bf(float f){
  union{float f; unsigned int i;} x; x.f = f;
  unsigned int r = x.i + 0x7fffu + ((x.i >> 16) & 1u);
  return (u16)(r >> 16);
}
__device__ __forceinline__ f32x4 MFMA(bf16x8 a, bf16x8 b, f32x4 c){
  return __builtin_amdgcn_mfma_f32_16x16x32_bf16(a, b, c, 0, 0, 0);
}

// ---------------- dtype sniff (bf16 vs f32 input buffers)
__global__ void detect_dtype(const u16* __restrict__ x, int* __restrict__ flag){
  if(threadIdx.x == 0 && blockIdx.x == 0){
    int cnt = 0;
    for(int i = 0; i < 64; i++){
      int e = (x[i] >> 7) & 0xFF;
      if(e >= 118 && e <= 136) cnt++;
    }
    *flag = (cnt >= 50) ? 1 : 0;   // 1 = bf16, 0 = f32
  }
}

// ---------------- dtype-aware convert to bf16
__global__ __launch_bounds__(256) void conv_bf(const void* __restrict__ src, u16* __restrict__ dst,
                                               long n, const int* __restrict__ flag){
  long i = ((long)blockIdx.x * 256 + threadIdx.x) * 8;
  if(i >= n) return;
  const int isbf = *flag;
  if(i + 8 <= n){
    if(isbf){
      *reinterpret_cast<u16x8*>(dst + i) = *reinterpret_cast<const u16x8*>((const u16*)src + i);
    }else{
      const float* s = (const float*)src + i;
      float4 a = *reinterpret_cast<const float4*>(s);
      float4 b = *reinterpret_cast<const float4*>(s + 4);
      u16x8 o;
      o[0]=f2bf(a.x); o[1]=f2bf(a.y); o[2]=f2bf(a.z); o[3]=f2bf(a.w);
      o[4]=f2bf(b.x); o[5]=f2bf(b.y); o[6]=f2bf(b.z); o[7]=f2bf(b.w);
      *reinterpret_cast<u16x8*>(dst + i) = o;
    }
  }else{
    for(long e = i; e < n; e++)
      dst[e] = isbf ? ((const u16*)src)[e] : f2bf(((const float*)src)[e]);
  }
}

// ---------------- zero fill
__global__ __launch_bounds__(256) void zero_f4(float* __restrict__ p, long n4){
  long i = (long)blockIdx.x * blockDim.x + threadIdx.x;
  if(i >= n4) return;
  float4 z = {0.f, 0.f, 0.f, 0.f};
  *reinterpret_cast<float4*>(p + i * 4) = z;
}

// ---------------- dtype-aware weight transpose: src [K,N] -> bf16 dst [n*256+k]
__global__ void wt_transpose(const void* __restrict__ src, u16* __restrict__ dst,
                             const int* __restrict__ flag){
  __shared__ u16 t[16][17];
  int m = blockIdx.z;
  int n0 = blockIdx.x * 16, k0 = blockIdx.y * 16;
  size_t sidx = (size_t)m * 65536 + (size_t)(k0 + threadIdx.y) * 256 + n0 + threadIdx.x;
  u16 v = (*flag) ? ((const u16*)src)[sidx] : f2bf(((const float*)src)[sidx]);
  t[threadIdx.y][threadIdx.x] = v;
  __syncthreads();
  dst[(size_t)m * 65536 + (size_t)(n0 + threadIdx.y) * 256 + (k0 + threadIdx.x)] =
      t[threadIdx.x][threadIdx.y];
}

// ---------------- dedup boundary incidences (.set(1.0): idempotent)
__global__ void dedup_kernel(const int* __restrict__ bb, const int* __restrict__ bi,
                             const int* __restrict__ bj, unsigned int* __restrict__ mask,
                             unsigned char* __restrict__ valid, int Q, int maxI, int maxJ){
  int q = blockIdx.x * blockDim.x + threadIdx.x;
  if(q >= Q) return;
  int s = (bb[q] * maxI + bi[q]) * maxJ + bj[q];
  unsigned int bit = 1u << (s & 31);
  unsigned int old = atomicOr(&mask[s >> 5], bit);
  valid[q] = (old & bit) ? 0 : 1;
}

// ---------------- CSR build: histogram
__global__ __launch_bounds__(256) void hist_up(const int* __restrict__ pb, const int* __restrict__ pi,
                                               int maxI, int segBase, int* __restrict__ hist, int P){
  int p = blockIdx.x * 256 + threadIdx.x;
  if(p >= P) return;
  atomicAdd(&hist[segBase + pb[p] * maxI + pi[p]], 1);
}
__global__ __launch_bounds__(256) void hist_bd(const int* __restrict__ bb, const int* __restrict__ bi,
                                               const unsigned char* __restrict__ valid,
                                               int maxI, int segBase, int* __restrict__ hist, int Q){
  int q = blockIdx.x * 256 + threadIdx.x;
  if(q >= Q || !valid[q]) return;
  atomicAdd(&hist[segBase + bb[q] * maxI + bi[q]], 1);
}

// ---------------- 3-phase exclusive scan over HTOT ints (1024 elems / block)
__global__ __launch_bounds__(256) void scan1(const int* __restrict__ hist, int* __restrict__ bsum){
  __shared__ int s[256];
  int t = threadIdx.x;
  long base = (long)blockIdx.x * 1024 + t * 4;
  int4 v = *reinterpret_cast<const int4*>(hist + base);
  s[t] = v.x + v.y + v.z + v.w;
  __syncthreads();
  for(int st = 128; st > 0; st >>= 1){
    if(t < st) s[t] += s[t + st];
    __syncthreads();
  }
  if(t == 0) bsum[blockIdx.x] = s[0];
}
__global__ __launch_bounds__(256) void scan2(int* __restrict__ bsum, int nb){
  __shared__ int s[256];
  int t = threadIdx.x;
  int v = (t < nb) ? bsum[t] : 0;
  s[t] = v;
  __syncthreads();
  for(int st = 1; st < 256; st <<= 1){
    int u = (t >= st) ? s[t - st] : 0;
    __syncthreads();
    s[t] += u;
    __syncthreads();
  }
  if(t < nb) bsum[t] = s[t] - v;   // exclusive
}
__global__ __launch_bounds__(256) void scan3(const int* __restrict__ hist, const int* __restrict__ bsum,
                                             int* __restrict__ off, int* __restrict__ cur){
  __shared__ int s[256];
  int t = threadIdx.x;
  long base = (long)blockIdx.x * 1024 + t * 4;
  int4 v = *reinterpret_cast<const int4*>(hist + base);
  int sum = v.x + v.y + v.z + v.w;
  s[t] = sum;
  __syncthreads();
  for(int st = 1; st < 256; st <<= 1){
    int u = (t >= st) ? s[t - st] : 0;
    __syncthreads();
    s[t] += u;
    __syncthreads();
  }
  int excl = s[t] - sum + bsum[blockIdx.x];
  int4 o;
  o.x = excl; o.y = o.x + v.x; o.z = o.y + v.y; o.w = o.z + v.z;
  *reinterpret_cast<int4*>(off + base) = o;
  *reinterpret_cast<int4*>(cur + base) = o;
}

// ---------------- CSR build: fill payloads (csrUp: global pos; csrBd: pos - UPTOT)
__global__ __launch_bounds__(256) void fill_up(const int* __restrict__ pb, const int* __restrict__ pi,
    const int* __restrict__ pj, const int* __restrict__ pa, int maxI, int maxA, int segBase,
    int* __restrict__ cur, int2* __restrict__ csrUp, int P){
  int p = blockIdx.x * 256 + threadIdx.x;
  if(p >= P) return;
  int b = pb[p];
  int pos = atomicAdd(&cur[segBase + b * maxI + pi[p]], 1);
  int2 e; e.x = b * maxI + pj[p]; e.y = b * maxA + pa[p];
  csrUp[pos] = e;
}
__global__ __launch_bounds__(256) void fill_bd(const int* __restrict__ bb, const int* __restrict__ bi,
    const int* __restrict__ bj, const unsigned char* __restrict__ valid, int maxI, int maxJ,
    int segBase, int* __restrict__ cur, int* __restrict__ csrBd, int Q){
  int q = blockIdx.x * 256 + threadIdx.x;
  if(q >= Q || !valid[q]) return;
  int b = bb[q];
  int pos = atomicAdd(&cur[segBase + b * maxI + bi[q]], 1);
  csrBd[pos - UPTOT] = b * maxJ + bj[q];
}

// ---------------- gather: one wave per receiver row, write ACC once (no atomics)
// up contribution: sum relu(Y[j] + Z[a]); bd contribution: sum BD[j].
template<int HAS_UP, int HAS_BD>
__global__ __launch_bounds__(256) void gather_k(
    const u16* __restrict__ Y, const u16* __restrict__ Z, const u16* __restrict__ BD,
    const int2* __restrict__ csrUp, const int* __restrict__ csrBd,
    const int* __restrict__ off, const int* __restrict__ deg,
    int upBase, int bdBase, float* __restrict__ ACC, int rowLo){
  const int row = rowLo + blockIdx.x * 4 + (threadIdx.x >> 6);
  const int lane = threadIdx.x & 63;
  const int c = lane * 4;
  float a0 = 0.f, a1 = 0.f, a2 = 0.f, a3 = 0.f;
  if(HAS_UP){
    int s = off[upBase + row];
    int d = deg[upBase + row];
    for(int k = 0; k < d; k++){
      int2 e = csrUp[s + k];
      const ushort4 y = *reinterpret_cast<const ushort4*>(Y + (size_t)e.x * 256 + c);
      const ushort4 z = *reinterpret_cast<const ushort4*>(Z + (size_t)e.y * 256 + c);
      a0 += fmaxf(bf2f(y.x) + bf2f(z.x), 0.f);
      a1 += fmaxf(bf2f(y.y) + bf2f(z.y), 0.f);
      a2 += fmaxf(bf2f(y.z) + bf2f(z.z), 0.f);
      a3 += fmaxf(bf2f(y.w) + bf2f(z.w), 0.f);
    }
  }
  if(HAS_BD){
    int s = off[bdBase + row] - UPTOT;
    int d = deg[bdBase + row];
    for(int k = 0; k < d; k++){
      int j = csrBd[s + k];
      const ushort4 x = *reinterpret_cast<const ushort4*>(BD + (size_t)j * 256 + c);
      a0 += bf2f(x.x); a1 += bf2f(x.y); a2 += bf2f(x.z); a3 += bf2f(x.w);
    }
  }
  float4 o = {a0, a1, a2, a3};
  *reinterpret_cast<float4*>(ACC + (size_t)(row - rowLo) * 256 + c) = o;
}

// ---------------- bf16 MFMA GEMM, 1-D grid over rows, N=K=256.
// MODE 0: C = A@W.  MODE 1: C = A@W + C (C != A).
// MODE 2: C = relu(A@W + ACC + bias), C may alias A (A preloaded + barrier).
template<int MODE>
__global__ __launch_bounds__(256) void gemm_k(const u16* A,
    const u16* __restrict__ WT, u16* C,
    const float* __restrict__ ACC, const u16* __restrict__ bias){
  const int lane = threadIdx.x & 63;
  const int wv = threadIdx.x >> 6;
  const int wm = wv >> 1, wn = wv & 1;
  const int r = lane & 15, q = lane >> 4;
  const int mbase = blockIdx.x * 64 + wm * 32;
  bf16x8 af[2][8];
  const u16* abase = A + (size_t)(mbase + r) * 256 + q * 8;
#pragma unroll
  for(int t = 0; t < 8; t++){
    af[0][t] = *reinterpret_cast<const bf16x8*>(abase + t * 32);
    af[1][t] = *reinterpret_cast<const bf16x8*>(abase + 16 * 256 + t * 32);
  }
  if(MODE == 2) __syncthreads();
  const int crow0 = mbase + q * 4;
#pragma unroll
  for(int nt = 0; nt < 4; nt++){
    const int ncol = wn * 128 + nt * 32;
    const u16* bbase = WT + (size_t)(ncol + r) * 256 + q * 8;
    f32x4 ac00 = {0.f,0.f,0.f,0.f};
    f32x4 ac01 = ac00, ac10 = ac00, ac11 = ac00;
#pragma unroll
    for(int t = 0; t < 8; t++){
      bf16x8 b0 = *reinterpret_cast<const bf16x8*>(bbase + t * 32);
      bf16x8 b1 = *reinterpret_cast<const bf16x8*>(bbase + 16 * 256 + t * 32);
      ac00 = MFMA(af[0][t], b0, ac00);
      ac01 = MFMA(af[0][t], b1, ac01);
      ac10 = MFMA(af[1][t], b0, ac10);
      ac11 = MFMA(af[1][t], b1, ac11);
    }
#pragma unroll
    for(int i = 0; i < 4; i++){
      float v[4] = {ac00[i], ac01[i], ac10[i], ac11[i]};
      const int rr[4] = {crow0 + i, crow0 + i, crow0 + 16 + i, crow0 + 16 + i};
      const int cc[4] = {ncol + r, ncol + 16 + r, ncol + r, ncol + 16 + r};
#pragma unroll
      for(int s = 0; s < 4; s++){
        const size_t idx = (size_t)rr[s] * 256 + cc[s];
        float x = v[s];
        if(MODE == 1) x += bf2f(C[idx]);
        if(MODE == 2) x = fmaxf(x + ACC[idx] + bf2f(bias[cc[s]]), 0.f);
        C[idx] = f2bf(x);
      }
    }
  }
}

// ---------------- pooled[b,h] += sum_r sigmoid(G+bp)[r,h] * X[r,h]
__global__ __launch_bounds__(256) void pool_reduce(const u16* __restrict__ G, const u16* __restrict__ bpv,
    const u16* __restrict__ X, float* __restrict__ pooled, int maxR, int rowsPerBlk){
  int b = blockIdx.x, h = threadIdx.x;
  int r0 = blockIdx.y * rowsPerBlk;
  float bias = bf2f(bpv[h]);
  float acc = 0.f;
  for(int r = r0; r < r0 + rowsPerBlk; r++){
    size_t o = ((size_t)b * maxR + r) * 256 + h;
    float t = bf2f(G[o]) + bias;
    float w = 1.f / (1.f + __expf(-t));
    acc += w * bf2f(X[o]);
  }
  atomicAdd(&pooled[b * 256 + h], acc);
}

// ---------------- h[b,o] = sum_i relu(pooled_i[b,:] @ W1[i] + b1[i])
__global__ __launch_bounds__(512) void readout1(const float* __restrict__ pooled, const u16* __restrict__ W1,
                                                const u16* __restrict__ b1, float* __restrict__ hbuf){
  __shared__ float p[3][256];
  int b = blockIdx.x, o = threadIdx.x;
  if(o < 256){
    p[0][o] = pooled[(size_t)b * 256 + o];
    p[1][o] = pooled[(size_t)NB * 256 + (size_t)b * 256 + o];
    p[2][o] = pooled[(size_t)2 * NB * 256 + (size_t)b * 256 + o];
  }
  __syncthreads();
  float s = 0.f;
#pragma unroll
  for(int i = 0; i < 3; i++){
    float a = bf2f(b1[i * 512 + o]);
    for(int k = 0; k < 256; k++) a += p[i][k] * bf2f(W1[(size_t)(i * 256 + k) * 512 + o]);
    s += fmaxf(a, 0.f);
  }
  hbuf[(size_t)b * 512 + o] = s;
}

// ---------------- out = h @ W2 + b2 (dtype-matched store)
__global__ __launch_bounds__(64) void readout2(const float* __restrict__ hbuf, const u16* __restrict__ W2,
                                               const u16* __restrict__ b2, void* __restrict__ out,
                                               const int* __restrict__ flag){
  int b = blockIdx.x, o = threadIdx.x;
  if(o >= 10) return;
  float a = bf2f(b2[o]);
  for(int k = 0; k < 512; k++) a += hbuf[(size_t)b * 512 + k] * bf2f(W2[k * 10 + o]);
  if(*flag) ((u16*)out)[b * 10 + o] = f2bf(a);
  else      ((float*)out)[b * 10 + o] = a;
}

extern "C" void kernel_launch(void* const* d_in, const int* in_sizes, int n_in,
                              void* d_out, int out_size, void* d_ws, size_t ws_size,
                              hipStream_t stream){
  const void* x_n = d_in[0];
  const void* x_e = d_in[1];
  const void* x_c = d_in[2];
  const int* n_up_b = (const int*)d_in[3];
  const int* n_up_i = (const int*)d_in[4];
  const int* n_up_j = (const int*)d_in[5];
  const int* n_up_e = (const int*)d_in[6];
  const int* e_up_b = (const int*)d_in[7];
  const int* e_up_i = (const int*)d_in[8];
  const int* e_up_j = (const int*)d_in[9];
  const int* e_up_c = (const int*)d_in[10];
  const int* eb_b = (const int*)d_in[11];
  const int* eb_i = (const int*)d_in[12];
  const int* eb_j = (const int*)d_in[13];
  const int* cb_b = (const int*)d_in[14];
  const int* cb_i = (const int*)d_in[15];
  const int* cb_j = (const int*)d_in[16];

  // ---- workspace carve-up (~141 MiB, below round-3/4 proven footprint)
  char* base = (char*)d_ws; size_t off0 = 0;
  auto alloc = [&](size_t n)->char*{ char* p = base + off0; off0 = (off0 + n + 255) & ~(size_t)255; return p; };
  u16* xn = (u16*)alloc((size_t)MN * HD * 2);
  u16* xe = (u16*)alloc((size_t)ME * HD * 2);
  u16* xc = (u16*)alloc((size_t)MC * HD * 2);
  u16* BIG1 = (u16*)alloc((size_t)ME * HD * 2);      // Ze/BDe/Ye/G staging
  u16* SMa  = (u16*)alloc((size_t)MN * HD * 2);      // Yn then Zc; pool: ref scratch (with SMb)
  u16* SMb  = (u16*)alloc((size_t)MN * HD * 2);      // BDn
  float* ACC = (float*)alloc((size_t)16384 * HD * 4);// 16 MiB: 16384-row chunks
  u16* wt = (u16*)alloc((size_t)38 * 65536 * 2);
  unsigned int* mask_e = (unsigned int*)alloc((size_t)NB * MAXE * MAXN / 8);  // dead after dedup -> params
  unsigned int* mask_c = (unsigned int*)alloc((size_t)NB * MAXC * MAXE / 8);
  unsigned char* valid_e = (unsigned char*)alloc(QE);
  unsigned char* valid_c = (unsigned char*)alloc(QC);
  float* pooled = (float*)alloc((size_t)3 * NB * HD * 4);   // also aliased as scan cursor
  float* hbuf   = (float*)alloc((size_t)NB * 512 * 4);
  int* flag     = (int*)alloc(256);
  int2* csrUp   = (int2*)alloc((size_t)UPTOT * 8);
  int* csrBd    = (int*)alloc((size_t)(QE + QC) * 4);
  int* hist     = (int*)alloc((size_t)HTOT * 4);
  int* offA     = (int*)alloc((size_t)HTOT * 4);
  int* bsum     = (int*)alloc(1024);
  int* cur      = (int*)pooled;   // 896 KB needed; pooled+hbuf = 1.25 MB, dead until pooling

  u16* wtSelf = wt;
  u16* wtUpx  = wt + (size_t)12 * 65536;
  u16* wtUpa  = wt + (size_t)20 * 65536;
  u16* wtB    = wt + (size_t)28 * 65536;
  u16* wtP    = wt + (size_t)36 * 65536;
  u16* wtPref = wt + (size_t)37 * 65536;

  // small converted params in mask_e's 1 MiB (dead after dedup)
  u16* W1c = (u16*)mask_e;
  u16* b1c = W1c + 393216;
  u16* W2c = b1c + 1536;
  u16* b2c = W2c + 5120;
  u16* bsc = b2c + 16;
  u16* bpc = bsc + 3072;

  auto convN = [&](const void* s, u16* d, long n){
    long blk = (n + 8*256 - 1) / (8*256);
    conv_bf<<<(int)blk, 256, 0, stream>>>(s, d, n, flag);
  };

  // ---- prologue
  detect_dtype<<<1, 64, 0, stream>>>((const u16*)x_n, flag);
  zero_f4<<<(65536 + 255)/256, 256, 0, stream>>>((float*)mask_e, 65536);
  zero_f4<<<(32768 + 255)/256, 256, 0, stream>>>((float*)mask_c, 32768);
  dedup_kernel<<<QE/256, 256, 0, stream>>>(eb_b, eb_i, eb_j, mask_e, valid_e, QE, MAXE, MAXN);
  dedup_kernel<<<QC/256, 256, 0, stream>>>(cb_b, cb_i, cb_j, mask_c, valid_c, QC, MAXC, MAXE);

  wt_transpose<<<dim3(16,16,12), dim3(16,16), 0, stream>>>(d_in[17], wtSelf, flag);
  wt_transpose<<<dim3(16,16,8),  dim3(16,16), 0, stream>>>(d_in[19], wtUpx,  flag);
  wt_transpose<<<dim3(16,16,8),  dim3(16,16), 0, stream>>>(d_in[20], wtUpa,  flag);
  wt_transpose<<<dim3(16,16,8),  dim3(16,16), 0, stream>>>(d_in[21], wtB,    flag);
  wt_transpose<<<dim3(16,16,1),  dim3(16,16), 0, stream>>>(d_in[22], wtP,    flag);
  wt_transpose<<<dim3(16,16,1),  dim3(16,16), 0, stream>>>(d_in[23], wtPref, flag);
  convN(x_n, xn, (long)MN * HD);
  convN(x_e, xe, (long)ME * HD);
  convN(x_c, xc, (long)MC * HD);
  convN(d_in[18], bsc, 3072);
  convN(d_in[24], bpc, 256);
  convN(d_in[25], W1c, 393216);
  convN(d_in[26], b1c, 1536);
  convN(d_in[27], W2c, 5120);
  convN(d_in[28], b2c, 10);

  // ---- CSR build (histogram -> scan -> fill)
  zero_f4<<<(HTOT/4 + 255)/256, 256, 0, stream>>>((float*)hist, HTOT/4);
  hist_up<<<PN/256, 256, 0, stream>>>(n_up_b, n_up_i, MAXN, SEG_N,  hist, PN);
  hist_up<<<PE/256, 256, 0, stream>>>(e_up_b, e_up_i, MAXE, SEG_E,  hist, PE);
  hist_bd<<<QE/256, 256, 0, stream>>>(eb_b, eb_i, valid_e, MAXE, SEG_EB, hist, QE);
  hist_bd<<<QC/256, 256, 0, stream>>>(cb_b, cb_i, valid_c, MAXC, SEG_CB, hist, QC);
  scan1<<<HTOT/1024, 256, 0, stream>>>(hist, bsum);
  scan2<<<1, 256, 0, stream>>>(bsum, HTOT/1024);
  scan3<<<HTOT/1024, 256, 0, stream>>>(hist, bsum, offA, cur);
  fill_up<<<PN/256, 256, 0, stream>>>(n_up_b, n_up_i, n_up_j, n_up_e, MAXN, MAXE, SEG_N, cur, csrUp, PN);
  fill_up<<<PE/256, 256, 0, stream>>>(e_up_b, e_up_i, e_up_j, e_up_c, MAXE, MAXC, SEG_E, cur, csrUp, PE);
  fill_bd<<<QE/256, 256, 0, stream>>>(eb_b, eb_i, eb_j, valid_e, MAXE, MAXN, SEG_EB, cur, csrBd, QE);
  fill_bd<<<QC/256, 256, 0, stream>>>(cb_b, cb_i, cb_j, valid_c, MAXC, MAXE, SEG_CB, cur, csrBd, QC);

  // ---- layers
  for(int l = 0; l < NLAYER; l++){
    const u16* Wupx0 = wtUpx + (size_t)(l*2+0) * 65536;
    const u16* Wupx1 = wtUpx + (size_t)(l*2+1) * 65536;
    const u16* Wupa0 = wtUpa + (size_t)(l*2+0) * 65536;
    const u16* Wupa1 = wtUpa + (size_t)(l*2+1) * 65536;
    const u16* Wb0   = wtB   + (size_t)(l*2+0) * 65536;
    const u16* Wb1   = wtB   + (size_t)(l*2+1) * 65536;
    const u16* Ws0   = wtSelf + (size_t)(l*3+0) * 65536;
    const u16* Ws1   = wtSelf + (size_t)(l*3+1) * 65536;
    const u16* Ws2   = wtSelf + (size_t)(l*3+2) * 65536;
    const u16* bs0 = bsc + (size_t)(l*3+0) * HD;
    const u16* bs1 = bsc + (size_t)(l*3+1) * HD;
    const u16* bs2 = bsc + (size_t)(l*3+2) * HD;

    // nodes: Yn (SMa), Ze (BIG1), BDn (SMb, held) from OLD features; then 2 halves
    gemm_k<0><<<MN/64, 256, 0, stream>>>(xn, Wupx0, SMa, nullptr, nullptr);
    gemm_k<0><<<ME/64, 256, 0, stream>>>(xe, Wupa0, BIG1, nullptr, nullptr);
    gemm_k<0><<<MN/64, 256, 0, stream>>>(xn, Wb0, SMb, nullptr, nullptr);
    for(int h = 0; h < 2; h++){
      int lo = h * (MN/2);
      gather_k<1,0><<<(MN/2)/4, 256, 0, stream>>>(SMa, BIG1, nullptr, csrUp, csrBd,
                                                  offA, hist, SEG_N, 0, ACC, lo);
      gemm_k<2><<<(MN/2)/64, 256, 0, stream>>>(xn + (size_t)lo * HD, Ws0,
                                               xn + (size_t)lo * HD, ACC, bs0);
    }

    // cells: Zc (SMa, held for edges), BDe (BIG1); gather + fused self
    gemm_k<0><<<MC/64, 256, 0, stream>>>(xc, Wupa1, SMa, nullptr, nullptr);
    gemm_k<0><<<ME/64, 256, 0, stream>>>(xe, Wb1, BIG1, nullptr, nullptr);
    gather_k<0,1><<<MC/4, 256, 0, stream>>>(nullptr, nullptr, BIG1, csrUp, csrBd,
                                            offA, hist, 0, SEG_CB, ACC, 0);
    gemm_k<2><<<MC/64, 256, 0, stream>>>(xc, Ws2, xc, ACC, bs2);

    // edges: Ye (BIG1) from OLD xe; 4 quarters of (up+bd gather, fused self)
    gemm_k<0><<<ME/64, 256, 0, stream>>>(xe, Wupx1, BIG1, nullptr, nullptr);
    for(int h = 0; h < 4; h++){
      int lo = h * (ME/4);
      gather_k<1,1><<<(ME/4)/4, 256, 0, stream>>>(BIG1, SMa, SMb, csrUp, csrBd,
                                                  offA, hist, SEG_E, SEG_EB, ACC, lo);
      gemm_k<2><<<(ME/4)/64, 256, 0, stream>>>(xe + (size_t)lo * HD, Ws1,
                                               xe + (size_t)lo * HD, ACC, bs1);
    }
  }

  // ---- gated pooling; refs re-converted from pristine d_in into SMa+SMb (contiguous 32 MiB)
  u16* REF = SMa;
  {
    long np4 = (long)3 * NB * HD / 4;
    zero_f4<<<(int)((np4 + 255)/256), 256, 0, stream>>>(pooled, np4);
  }
  gemm_k<0><<<MN/64, 256, 0, stream>>>(xn, wtP, BIG1, nullptr, nullptr);
  convN(x_n, REF, (long)MN * HD);
  gemm_k<1><<<MN/64, 256, 0, stream>>>(REF, wtPref, BIG1, nullptr, nullptr);
  pool_reduce<<<dim3(NB,2), 256, 0, stream>>>(BIG1, bpc, xn, pooled, MAXN, MAXN/2);

  gemm_k<0><<<ME/64, 256, 0, stream>>>(xe, wtP, BIG1, nullptr, nullptr);
  convN(x_e, REF, (long)ME * HD);
  gemm_k<1><<<ME/64, 256, 0, stream>>>(REF, wtPref, BIG1, nullptr, nullptr);
  pool_reduce<<<dim3(NB,4), 256, 0, stream>>>(BIG1, bpc, xe, pooled + (size_t)NB*HD, MAXE, MAXE/4);

  gemm_k<0><<<MC/64, 256, 0, stream>>>(xc, wtP, BIG1, nullptr, nullptr);
  convN(x_c, REF, (long)MC * HD);
  gemm_k<1><<<MC/64, 256, 0, stream>>>(REF, wtPref, BIG1, nullptr, nullptr);
  pool_reduce<<<dim3(NB,1), 256, 0, stream>>>(BIG1, bpc, xc, pooled + (size_t)2*NB*HD, MAXC, MAXC);

  // ---- readout
  readout1<<<NB, 512, 0, stream>>>(pooled, W1c, b1c, hbuf);
  readout2<<<NB, 64, 0, stream>>>(hbuf, W2c, b2c, d_out, flag);
}

// Round 6
// 1791.249 us; speedup vs baseline: 4.2070x; 1.2742x over previous
//
#include <hip/hip_runtime.h>
#include <cstdint>
#include <cstddef>

typedef unsigned short u16;
typedef __bf16 bf16x8 __attribute__((ext_vector_type(8)));
typedef float f32x4 __attribute__((ext_vector_type(4)));
typedef unsigned short u16x8 __attribute__((ext_vector_type(8)));

#define NB   256
#define MAXN 128
#define MAXE 256
#define MAXC 64
#define HD   256
#define NLAYER 4
#define PN 131072
#define PE 98304
#define QE 131072
#define QC 65536
#define MN (NB*MAXN)   /* 32768 node rows  */
#define ME (NB*MAXE)   /* 65536 edge rows  */
#define MC (NB*MAXC)   /* 16384 cell rows  */

// CSR segment bases in the concatenated histogram/offset arrays
#define SEG_N  0
#define SEG_E  (MN)
#define SEG_EB (MN + ME)
#define SEG_CB (MN + 2*ME)
#define HTOT   (MN + 2*ME + MC)      /* 229376, divisible by 1024 */
#define UPTOT  (PN + PE)             /* csrBd global-index base   */

__device__ __forceinline__ float bf2f(u16 u){
  union{unsigned int i; float f;} x; x.i = ((unsigned int)u) << 16; return x.f;
}
__device__ __forceinline__ u16 f2bf(float f){
  union{float f; unsigned int i;} x; x.f = f;
  unsigned int r = x.i + 0x7fffu + ((x.i >> 16) & 1u);
  return (u16)(r >> 16);
}
__device__ __forceinline__ f32x4 MFMA(bf16x8 a, bf16x8 b, f32x4 c){
  return __builtin_amdgcn_mfma_f32_16x16x32_bf16(a, b, c, 0, 0, 0);
}
// async global->LDS, 16B per lane; lds base must be wave-uniform (lane*16 implicit)
__device__ __forceinline__ void gl_lds16(const u16* g, u16* l){
  __builtin_amdgcn_global_load_lds(
      (const __attribute__((address_space(1))) unsigned int*)g,
      (__attribute__((address_space(3))) unsigned int*)l, 16, 0, 0);
}

// ---------------- dtype sniff (bf16 vs f32 input buffers)
__global__ void detect_dtype(const u16* __restrict__ x, int* __restrict__ flag){
  if(threadIdx.x == 0 && blockIdx.x == 0){
    int cnt = 0;
    for(int i = 0; i < 64; i++){
      int e = (x[i] >> 7) & 0xFF;
      if(e >= 118 && e <= 136) cnt++;
    }
    *flag = (cnt >= 50) ? 1 : 0;   // 1 = bf16, 0 = f32
  }
}

// ---------------- dtype-aware convert to bf16
__global__ __launch_bounds__(256) void conv_bf(const void* __restrict__ src, u16* __restrict__ dst,
                                               long n, const int* __restrict__ flag){
  long i = ((long)blockIdx.x * 256 + threadIdx.x) * 8;
  if(i >= n) return;
  const int isbf = *flag;
  if(i + 8 <= n){
    if(isbf){
      *reinterpret_cast<u16x8*>(dst + i) = *reinterpret_cast<const u16x8*>((const u16*)src + i);
    }else{
      const float* s = (const float*)src + i;
      float4 a = *reinterpret_cast<const float4*>(s);
      float4 b = *reinterpret_cast<const float4*>(s + 4);
      u16x8 o;
      o[0]=f2bf(a.x); o[1]=f2bf(a.y); o[2]=f2bf(a.z); o[3]=f2bf(a.w);
      o[4]=f2bf(b.x); o[5]=f2bf(b.y); o[6]=f2bf(b.z); o[7]=f2bf(b.w);
      *reinterpret_cast<u16x8*>(dst + i) = o;
    }
  }else{
    for(long e = i; e < n; e++)
      dst[e] = isbf ? ((const u16*)src)[e] : f2bf(((const float*)src)[e]);
  }
}

// ---------------- zero fill
__global__ __launch_bounds__(256) void zero_f4(float* __restrict__ p, long n4){
  long i = (long)blockIdx.x * blockDim.x + threadIdx.x;
  if(i >= n4) return;
  float4 z = {0.f, 0.f, 0.f, 0.f};
  *reinterpret_cast<float4*>(p + i * 4) = z;
}

// ---------------- dtype-aware weight transpose: src [K,N] -> bf16 dst [n*256+k]
__global__ void wt_transpose(const void* __restrict__ src, u16* __restrict__ dst,
                             const int* __restrict__ flag){
  __shared__ u16 t[16][17];
  int m = blockIdx.z;
  int n0 = blockIdx.x * 16, k0 = blockIdx.y * 16;
  size_t sidx = (size_t)m * 65536 + (size_t)(k0 + threadIdx.y) * 256 + n0 + threadIdx.x;
  u16 v = (*flag) ? ((const u16*)src)[sidx] : f2bf(((const float*)src)[sidx]);
  t[threadIdx.y][threadIdx.x] = v;
  __syncthreads();
  dst[(size_t)m * 65536 + (size_t)(n0 + threadIdx.y) * 256 + (k0 + threadIdx.x)] =
      t[threadIdx.x][threadIdx.y];
}

// ---------------- dedup boundary incidences (.set(1.0): idempotent)
__global__ void dedup_kernel(const int* __restrict__ bb, const int* __restrict__ bi,
                             const int* __restrict__ bj, unsigned int* __restrict__ mask,
                             unsigned char* __restrict__ valid, int Q, int maxI, int maxJ){
  int q = blockIdx.x * blockDim.x + threadIdx.x;
  if(q >= Q) return;
  int s = (bb[q] * maxI + bi[q]) * maxJ + bj[q];
  unsigned int bit = 1u << (s & 31);
  unsigned int old = atomicOr(&mask[s >> 5], bit);
  valid[q] = (old & bit) ? 0 : 1;
}

// ---------------- CSR build: histogram
__global__ __launch_bounds__(256) void hist_up(const int* __restrict__ pb, const int* __restrict__ pi,
                                               int maxI, int segBase, int* __restrict__ hist, int P){
  int p = blockIdx.x * 256 + threadIdx.x;
  if(p >= P) return;
  atomicAdd(&hist[segBase + pb[p] * maxI + pi[p]], 1);
}
__global__ __launch_bounds__(256) void hist_bd(const int* __restrict__ bb, const int* __restrict__ bi,
                                               const unsigned char* __restrict__ valid,
                                               int maxI, int segBase, int* __restrict__ hist, int Q){
  int q = blockIdx.x * 256 + threadIdx.x;
  if(q >= Q || !valid[q]) return;
  atomicAdd(&hist[segBase + bb[q] * maxI + bi[q]], 1);
}

// ---------------- 3-phase exclusive scan over HTOT ints (1024 elems / block)
__global__ __launch_bounds__(256) void scan1(const int* __restrict__ hist, int* __restrict__ bsum){
  __shared__ int s[256];
  int t = threadIdx.x;
  long base = (long)blockIdx.x * 1024 + t * 4;
  int4 v = *reinterpret_cast<const int4*>(hist + base);
  s[t] = v.x + v.y + v.z + v.w;
  __syncthreads();
  for(int st = 128; st > 0; st >>= 1){
    if(t < st) s[t] += s[t + st];
    __syncthreads();
  }
  if(t == 0) bsum[blockIdx.x] = s[0];
}
__global__ __launch_bounds__(256) void scan2(int* __restrict__ bsum, int nb){
  __shared__ int s[256];
  int t = threadIdx.x;
  int v = (t < nb) ? bsum[t] : 0;
  s[t] = v;
  __syncthreads();
  for(int st = 1; st < 256; st <<= 1){
    int u = (t >= st) ? s[t - st] : 0;
    __syncthreads();
    s[t] += u;
    __syncthreads();
  }
  if(t < nb) bsum[t] = s[t] - v;   // exclusive
}
__global__ __launch_bounds__(256) void scan3(const int* __restrict__ hist, const int* __restrict__ bsum,
                                             int* __restrict__ off, int* __restrict__ cur){
  __shared__ int s[256];
  int t = threadIdx.x;
  long base = (long)blockIdx.x * 1024 + t * 4;
  int4 v = *reinterpret_cast<const int4*>(hist + base);
  int sum = v.x + v.y + v.z + v.w;
  s[t] = sum;
  __syncthreads();
  for(int st = 1; st < 256; st <<= 1){
    int u = (t >= st) ? s[t - st] : 0;
    __syncthreads();
    s[t] += u;
    __syncthreads();
  }
  int excl = s[t] - sum + bsum[blockIdx.x];
  int4 o;
  o.x = excl; o.y = o.x + v.x; o.z = o.y + v.y; o.w = o.z + v.z;
  *reinterpret_cast<int4*>(off + base) = o;
  *reinterpret_cast<int4*>(cur + base) = o;
}

// ---------------- CSR build: fill payloads (csrUp: global pos; csrBd: pos - UPTOT)
__global__ __launch_bounds__(256) void fill_up(const int* __restrict__ pb, const int* __restrict__ pi,
    const int* __restrict__ pj, const int* __restrict__ pa, int maxI, int maxA, int segBase,
    int* __restrict__ cur, int2* __restrict__ csrUp, int P){
  int p = blockIdx.x * 256 + threadIdx.x;
  if(p >= P) return;
  int b = pb[p];
  int pos = atomicAdd(&cur[segBase + b * maxI + pi[p]], 1);
  int2 e; e.x = b * maxI + pj[p]; e.y = b * maxA + pa[p];
  csrUp[pos] = e;
}
__global__ __launch_bounds__(256) void fill_bd(const int* __restrict__ bb, const int* __restrict__ bi,
    const int* __restrict__ bj, const unsigned char* __restrict__ valid, int maxI, int maxJ,
    int segBase, int* __restrict__ cur, int* __restrict__ csrBd, int Q){
  int q = blockIdx.x * 256 + threadIdx.x;
  if(q >= Q || !valid[q]) return;
  int b = bb[q];
  int pos = atomicAdd(&cur[segBase + b * maxI + bi[q]], 1);
  csrBd[pos - UPTOT] = b * maxJ + bj[q];
}

// ---------------- gather: one wave per receiver row, write ACC once (no atomics)
template<int HAS_UP, int HAS_BD>
__global__ __launch_bounds__(256) void gather_k(
    const u16* __restrict__ Y, const u16* __restrict__ Z, const u16* __restrict__ BD,
    const int2* __restrict__ csrUp, const int* __restrict__ csrBd,
    const int* __restrict__ off, const int* __restrict__ deg,
    int upBase, int bdBase, float* __restrict__ ACC, int rowLo){
  const int row = rowLo + blockIdx.x * 4 + (threadIdx.x >> 6);
  const int lane = threadIdx.x & 63;
  const int c = lane * 4;
  float a0 = 0.f, a1 = 0.f, a2 = 0.f, a3 = 0.f;
  if(HAS_UP){
    int s = off[upBase + row];
    int d = deg[upBase + row];
    for(int k = 0; k < d; k++){
      int2 e = csrUp[s + k];
      const ushort4 y = *reinterpret_cast<const ushort4*>(Y + (size_t)e.x * 256 + c);
      const ushort4 z = *reinterpret_cast<const ushort4*>(Z + (size_t)e.y * 256 + c);
      a0 += fmaxf(bf2f(y.x) + bf2f(z.x), 0.f);
      a1 += fmaxf(bf2f(y.y) + bf2f(z.y), 0.f);
      a2 += fmaxf(bf2f(y.z) + bf2f(z.z), 0.f);
      a3 += fmaxf(bf2f(y.w) + bf2f(z.w), 0.f);
    }
  }
  if(HAS_BD){
    int s = off[bdBase + row] - UPTOT;
    int d = deg[bdBase + row];
    for(int k = 0; k < d; k++){
      int j = csrBd[s + k];
      const ushort4 x = *reinterpret_cast<const ushort4*>(BD + (size_t)j * 256 + c);
      a0 += bf2f(x.x); a1 += bf2f(x.y); a2 += bf2f(x.z); a3 += bf2f(x.w);
    }
  }
  float4 o = {a0, a1, a2, a3};
  *reinterpret_cast<float4*>(ACC + (size_t)(row - rowLo) * 256 + c) = o;
}

// ---------------- m97-style LDS-staged bf16 MFMA GEMM. Block = 512 thr (8 waves),
// tile 128 rows x 256 cols (full N), K staged in BK=64 chunks via global_load_lds.
// MODE 0: C = A@W.  MODE 1: C = A@W + C (C != A).
// MODE 2: C = relu(A@W + ACC + bias); C may alias A (1-D row-disjoint grid + full-N
//         block: all A reads for this block's rows complete before its C writes).
template<int MODE>
__global__ __launch_bounds__(512) void gemm_b(const u16* A, const u16* __restrict__ WT,
                                              u16* C, const float* __restrict__ ACC,
                                              const u16* __restrict__ bias){
  __shared__ u16 lA[128 * 64];   // [row][k], 128 B/row
  __shared__ u16 lB[256 * 64];   // [n][k]
  const int t = threadIdx.x;
  const int lane = t & 63, wv = t >> 6;
  const int wm = wv >> 2, wn = wv & 3;        // 2 x 4 wave grid, each 64x64
  const int r = lane & 15, q = lane >> 4;
  const size_t m0 = (size_t)blockIdx.x * 128;
  const int lrow = lane >> 3, lchk = lane & 7; // 8 rows x 8 chunks of 16B per wave-issue

  f32x4 acc[4][4];
#pragma unroll
  for(int i = 0; i < 4; i++)
#pragma unroll
    for(int j = 0; j < 4; j++) acc[i][j] = {0.f, 0.f, 0.f, 0.f};

#pragma unroll
  for(int k0 = 0; k0 < 256; k0 += 64){
    // stage A: 16 KB = 2 issues x (8 waves x 1 KB)
#pragma unroll
    for(int i = 0; i < 2; i++){
      const int row = i * 64 + wv * 8 + lrow;
      gl_lds16(A + (m0 + row) * 256 + k0 + lchk * 8, lA + (i * 64 + wv * 8) * 64);
    }
    // stage B: 32 KB = 4 issues
#pragma unroll
    for(int j = 0; j < 4; j++){
      const int n = j * 64 + wv * 8 + lrow;
      gl_lds16(WT + (size_t)n * 256 + k0 + lchk * 8, lB + (j * 64 + wv * 8) * 64);
    }
    __syncthreads();   // drains vmcnt for global_load_lds
#pragma unroll
    for(int ks = 0; ks < 2; ks++){
      bf16x8 af[4], bf[4];
#pragma unroll
      for(int i = 0; i < 4; i++)
        af[i] = *reinterpret_cast<const bf16x8*>(lA + (wm * 64 + i * 16 + r) * 64 + ks * 32 + q * 8);
#pragma unroll
      for(int j = 0; j < 4; j++)
        bf[j] = *reinterpret_cast<const bf16x8*>(lB + (wn * 64 + j * 16 + r) * 64 + ks * 32 + q * 8);
#pragma unroll
      for(int i = 0; i < 4; i++)
#pragma unroll
        for(int j = 0; j < 4; j++) acc[i][j] = MFMA(af[i], bf[j], acc[i][j]);
    }
    __syncthreads();   // LDS reuse next k0
  }

  // epilogue: C/D layout col = lane&15, row = (lane>>4)*4 + reg
#pragma unroll
  for(int i = 0; i < 4; i++){
    const size_t row0 = m0 + wm * 64 + i * 16 + q * 4;
#pragma unroll
    for(int j = 0; j < 4; j++){
      const int col = wn * 64 + j * 16 + r;
#pragma unroll
      for(int reg = 0; reg < 4; reg++){
        const size_t idx = (row0 + reg) * 256 + col;
        float x = acc[i][j][reg];
        if(MODE == 1) x += bf2f(C[idx]);
        if(MODE == 2) x = fmaxf(x + ACC[idx] + bf2f(bias[col]), 0.f);
        C[idx] = f2bf(x);
      }
    }
  }
}

// ---------------- pooled[b,h] += sum_r sigmoid(G+bp)[r,h] * X[r,h]
__global__ __launch_bounds__(256) void pool_reduce(const u16* __restrict__ G, const u16* __restrict__ bpv,
    const u16* __restrict__ X, float* __restrict__ pooled, int maxR, int rowsPerBlk){
  int b = blockIdx.x, h = threadIdx.x;
  int r0 = blockIdx.y * rowsPerBlk;
  float bias = bf2f(bpv[h]);
  float acc = 0.f;
  for(int r = r0; r < r0 + rowsPerBlk; r++){
    size_t o = ((size_t)b * maxR + r) * 256 + h;
    float t = bf2f(G[o]) + bias;
    float w = 1.f / (1.f + __expf(-t));
    acc += w * bf2f(X[o]);
  }
  atomicAdd(&pooled[b * 256 + h], acc);
}

// ---------------- h[b,o] = sum_i relu(pooled_i[b,:] @ W1[i] + b1[i])
__global__ __launch_bounds__(512) void readout1(const float* __restrict__ pooled, const u16* __restrict__ W1,
                                                const u16* __restrict__ b1, float* __restrict__ hbuf){
  __shared__ float p[3][256];
  int b = blockIdx.x, o = threadIdx.x;
  if(o < 256){
    p[0][o] = pooled[(size_t)b * 256 + o];
    p[1][o] = pooled[(size_t)NB * 256 + (size_t)b * 256 + o];
    p[2][o] = pooled[(size_t)2 * NB * 256 + (size_t)b * 256 + o];
  }
  __syncthreads();
  float s = 0.f;
#pragma unroll
  for(int i = 0; i < 3; i++){
    float a = bf2f(b1[i * 512 + o]);
    for(int k = 0; k < 256; k++) a += p[i][k] * bf2f(W1[(size_t)(i * 256 + k) * 512 + o]);
    s += fmaxf(a, 0.f);
  }
  hbuf[(size_t)b * 512 + o] = s;
}

// ---------------- out = h @ W2 + b2 (dtype-matched store)
__global__ __launch_bounds__(64) void readout2(const float* __restrict__ hbuf, const u16* __restrict__ W2,
                                               const u16* __restrict__ b2, void* __restrict__ out,
                                               const int* __restrict__ flag){
  int b = blockIdx.x, o = threadIdx.x;
  if(o >= 10) return;
  float a = bf2f(b2[o]);
  for(int k = 0; k < 512; k++) a += hbuf[(size_t)b * 512 + k] * bf2f(W2[k * 10 + o]);
  if(*flag) ((u16*)out)[b * 10 + o] = f2bf(a);
  else      ((float*)out)[b * 10 + o] = a;
}

extern "C" void kernel_launch(void* const* d_in, const int* in_sizes, int n_in,
                              void* d_out, int out_size, void* d_ws, size_t ws_size,
                              hipStream_t stream){
  const void* x_n = d_in[0];
  const void* x_e = d_in[1];
  const void* x_c = d_in[2];
  const int* n_up_b = (const int*)d_in[3];
  const int* n_up_i = (const int*)d_in[4];
  const int* n_up_j = (const int*)d_in[5];
  const int* n_up_e = (const int*)d_in[6];
  const int* e_up_b = (const int*)d_in[7];
  const int* e_up_i = (const int*)d_in[8];
  const int* e_up_j = (const int*)d_in[9];
  const int* e_up_c = (const int*)d_in[10];
  const int* eb_b = (const int*)d_in[11];
  const int* eb_i = (const int*)d_in[12];
  const int* eb_j = (const int*)d_in[13];
  const int* cb_b = (const int*)d_in[14];
  const int* cb_i = (const int*)d_in[15];
  const int* cb_j = (const int*)d_in[16];

  // ---- workspace carve-up (~141 MiB, proven footprint)
  char* base = (char*)d_ws; size_t off0 = 0;
  auto alloc = [&](size_t n)->char*{ char* p = base + off0; off0 = (off0 + n + 255) & ~(size_t)255; return p; };
  u16* xn = (u16*)alloc((size_t)MN * HD * 2);
  u16* xe = (u16*)alloc((size_t)ME * HD * 2);
  u16* xc = (u16*)alloc((size_t)MC * HD * 2);
  u16* BIG1 = (u16*)alloc((size_t)ME * HD * 2);      // Ze/BDe/Ye/G staging
  u16* SMa  = (u16*)alloc((size_t)MN * HD * 2);      // Yn then Zc; pool: ref scratch
  u16* SMb  = (u16*)alloc((size_t)MN * HD * 2);      // BDn
  float* ACC = (float*)alloc((size_t)16384 * HD * 4);// 16 MiB: 16384-row chunks
  u16* wt = (u16*)alloc((size_t)38 * 65536 * 2);
  unsigned int* mask_e = (unsigned int*)alloc((size_t)NB * MAXE * MAXN / 8);  // dead after dedup -> params
  unsigned int* mask_c = (unsigned int*)alloc((size_t)NB * MAXC * MAXE / 8);
  unsigned char* valid_e = (unsigned char*)alloc(QE);
  unsigned char* valid_c = (unsigned char*)alloc(QC);
  float* pooled = (float*)alloc((size_t)3 * NB * HD * 4);   // also aliased as scan cursor
  float* hbuf   = (float*)alloc((size_t)NB * 512 * 4);
  int* flag     = (int*)alloc(256);
  int2* csrUp   = (int2*)alloc((size_t)UPTOT * 8);
  int* csrBd    = (int*)alloc((size_t)(QE + QC) * 4);
  int* hist     = (int*)alloc((size_t)HTOT * 4);
  int* offA     = (int*)alloc((size_t)HTOT * 4);
  int* bsum     = (int*)alloc(1024);
  int* cur      = (int*)pooled;   // scan cursor; pooled dead until pooling

  u16* wtSelf = wt;
  u16* wtUpx  = wt + (size_t)12 * 65536;
  u16* wtUpa  = wt + (size_t)20 * 65536;
  u16* wtB    = wt + (size_t)28 * 65536;
  u16* wtP    = wt + (size_t)36 * 65536;
  u16* wtPref = wt + (size_t)37 * 65536;

  // small converted params in mask_e's 1 MiB (dead after dedup)
  u16* W1c = (u16*)mask_e;
  u16* b1c = W1c + 393216;
  u16* W2c = b1c + 1536;
  u16* b2c = W2c + 5120;
  u16* bsc = b2c + 16;
  u16* bpc = bsc + 3072;

  auto convN = [&](const void* s, u16* d, long n){
    long blk = (n + 8*256 - 1) / (8*256);
    conv_bf<<<(int)blk, 256, 0, stream>>>(s, d, n, flag);
  };

  // ---- prologue
  detect_dtype<<<1, 64, 0, stream>>>((const u16*)x_n, flag);
  zero_f4<<<(65536 + 255)/256, 256, 0, stream>>>((float*)mask_e, 65536);
  zero_f4<<<(32768 + 255)/256, 256, 0, stream>>>((float*)mask_c, 32768);
  dedup_kernel<<<QE/256, 256, 0, stream>>>(eb_b, eb_i, eb_j, mask_e, valid_e, QE, MAXE, MAXN);
  dedup_kernel<<<QC/256, 256, 0, stream>>>(cb_b, cb_i, cb_j, mask_c, valid_c, QC, MAXC, MAXE);

  wt_transpose<<<dim3(16,16,12), dim3(16,16), 0, stream>>>(d_in[17], wtSelf, flag);
  wt_transpose<<<dim3(16,16,8),  dim3(16,16), 0, stream>>>(d_in[19], wtUpx,  flag);
  wt_transpose<<<dim3(16,16,8),  dim3(16,16), 0, stream>>>(d_in[20], wtUpa,  flag);
  wt_transpose<<<dim3(16,16,8),  dim3(16,16), 0, stream>>>(d_in[21], wtB,    flag);
  wt_transpose<<<dim3(16,16,1),  dim3(16,16), 0, stream>>>(d_in[22], wtP,    flag);
  wt_transpose<<<dim3(16,16,1),  dim3(16,16), 0, stream>>>(d_in[23], wtPref, flag);
  convN(x_n, xn, (long)MN * HD);
  convN(x_e, xe, (long)ME * HD);
  convN(x_c, xc, (long)MC * HD);
  convN(d_in[18], bsc, 3072);
  convN(d_in[24], bpc, 256);
  convN(d_in[25], W1c, 393216);
  convN(d_in[26], b1c, 1536);
  convN(d_in[27], W2c, 5120);
  convN(d_in[28], b2c, 10);

  // ---- CSR build (histogram -> scan -> fill)
  zero_f4<<<(HTOT/4 + 255)/256, 256, 0, stream>>>((float*)hist, HTOT/4);
  hist_up<<<PN/256, 256, 0, stream>>>(n_up_b, n_up_i, MAXN, SEG_N,  hist, PN);
  hist_up<<<PE/256, 256, 0, stream>>>(e_up_b, e_up_i, MAXE, SEG_E,  hist, PE);
  hist_bd<<<QE/256, 256, 0, stream>>>(eb_b, eb_i, valid_e, MAXE, SEG_EB, hist, QE);
  hist_bd<<<QC/256, 256, 0, stream>>>(cb_b, cb_i, valid_c, MAXC, SEG_CB, hist, QC);
  scan1<<<HTOT/1024, 256, 0, stream>>>(hist, bsum);
  scan2<<<1, 256, 0, stream>>>(bsum, HTOT/1024);
  scan3<<<HTOT/1024, 256, 0, stream>>>(hist, bsum, offA, cur);
  fill_up<<<PN/256, 256, 0, stream>>>(n_up_b, n_up_i, n_up_j, n_up_e, MAXN, MAXE, SEG_N, cur, csrUp, PN);
  fill_up<<<PE/256, 256, 0, stream>>>(e_up_b, e_up_i, e_up_j, e_up_c, MAXE, MAXC, SEG_E, cur, csrUp, PE);
  fill_bd<<<QE/256, 256, 0, stream>>>(eb_b, eb_i, eb_j, valid_e, MAXE, MAXN, SEG_EB, cur, csrBd, QE);
  fill_bd<<<QC/256, 256, 0, stream>>>(cb_b, cb_i, cb_j, valid_c, MAXC, MAXE, SEG_CB, cur, csrBd, QC);

  // ---- layers
  for(int l = 0; l < NLAYER; l++){
    const u16* Wupx0 = wtUpx + (size_t)(l*2+0) * 65536;
    const u16* Wupx1 = wtUpx + (size_t)(l*2+1) * 65536;
    const u16* Wupa0 = wtUpa + (size_t)(l*2+0) * 65536;
    const u16* Wupa1 = wtUpa + (size_t)(l*2+1) * 65536;
    const u16* Wb0   = wtB   + (size_t)(l*2+0) * 65536;
    const u16* Wb1   = wtB   + (size_t)(l*2+1) * 65536;
    const u16* Ws0   = wtSelf + (size_t)(l*3+0) * 65536;
    const u16* Ws1   = wtSelf + (size_t)(l*3+1) * 65536;
    const u16* Ws2   = wtSelf + (size_t)(l*3+2) * 65536;
    const u16* bs0 = bsc + (size_t)(l*3+0) * HD;
    const u16* bs1 = bsc + (size_t)(l*3+1) * HD;
    const u16* bs2 = bsc + (size_t)(l*3+2) * HD;

    // nodes: Yn (SMa), Ze (BIG1), BDn (SMb, held) from OLD features; then 2 halves
    gemm_b<0><<<MN/128, 512, 0, stream>>>(xn, Wupx0, SMa, nullptr, nullptr);
    gemm_b<0><<<ME/128, 512, 0, stream>>>(xe, Wupa0, BIG1, nullptr, nullptr);
    gemm_b<0><<<MN/128, 512, 0, stream>>>(xn, Wb0, SMb, nullptr, nullptr);
    for(int h = 0; h < 2; h++){
      int lo = h * (MN/2);
      gather_k<1,0><<<(MN/2)/4, 256, 0, stream>>>(SMa, BIG1, nullptr, csrUp, csrBd,
                                                  offA, hist, SEG_N, 0, ACC, lo);
      gemm_b<2><<<(MN/2)/128, 512, 0, stream>>>(xn + (size_t)lo * HD, Ws0,
                                                xn + (size_t)lo * HD, ACC, bs0);
    }

    // cells: Zc (SMa, held for edges), BDe (BIG1); gather + fused self
    gemm_b<0><<<MC/128, 512, 0, stream>>>(xc, Wupa1, SMa, nullptr, nullptr);
    gemm_b<0><<<ME/128, 512, 0, stream>>>(xe, Wb1, BIG1, nullptr, nullptr);
    gather_k<0,1><<<MC/4, 256, 0, stream>>>(nullptr, nullptr, BIG1, csrUp, csrBd,
                                            offA, hist, 0, SEG_CB, ACC, 0);
    gemm_b<2><<<MC/128, 512, 0, stream>>>(xc, Ws2, xc, ACC, bs2);

    // edges: Ye (BIG1) from OLD xe; 4 quarters of (up+bd gather, fused self)
    gemm_b<0><<<ME/128, 512, 0, stream>>>(xe, Wupx1, BIG1, nullptr, nullptr);
    for(int h = 0; h < 4; h++){
      int lo = h * (ME/4);
      gather_k<1,1><<<(ME/4)/4, 256, 0, stream>>>(BIG1, SMa, SMb, csrUp, csrBd,
                                                  offA, hist, SEG_E, SEG_EB, ACC, lo);
      gemm_b<2><<<(ME/4)/128, 512, 0, stream>>>(xe + (size_t)lo * HD, Ws1,
                                                xe + (size_t)lo * HD, ACC, bs1);
    }
  }

  // ---- gated pooling; refs re-converted from pristine d_in into SMa+SMb
  u16* REF = SMa;
  {
    long np4 = (long)3 * NB * HD / 4;
    zero_f4<<<(int)((np4 + 255)/256), 256, 0, stream>>>(pooled, np4);
  }
  gemm_b<0><<<MN/128, 512, 0, stream>>>(xn, wtP, BIG1, nullptr, nullptr);
  convN(x_n, REF, (long)MN * HD);
  gemm_b<1><<<MN/128, 512, 0, stream>>>(REF, wtPref, BIG1, nullptr, nullptr);
  pool_reduce<<<dim3(NB,2), 256, 0, stream>>>(BIG1, bpc, xn, pooled, MAXN, MAXN/2);

  gemm_b<0><<<ME/128, 512, 0, stream>>>(xe, wtP, BIG1, nullptr, nullptr);
  convN(x_e, REF, (long)ME * HD);
  gemm_b<1><<<ME/128, 512, 0, stream>>>(REF, wtPref, BIG1, nullptr, nullptr);
  pool_reduce<<<dim3(NB,4), 256, 0, stream>>>(BIG1, bpc, xe, pooled + (size_t)NB*HD, MAXE, MAXE/4);

  gemm_b<0><<<MC/128, 512, 0, stream>>>(xc, wtP, BIG1, nullptr, nullptr);
  convN(x_c, REF, (long)MC * HD);
  gemm_b<1><<<MC/128, 512, 0, stream>>>(REF, wtPref, BIG1, nullptr, nullptr);
  pool_reduce<<<dim3(NB,1), 256, 0, stream>>>(BIG1, bpc, xc, pooled + (size_t)2*NB*HD, MAXC, MAXC);

  // ---- readout
  readout1<<<NB, 512, 0, stream>>>(pooled, W1c, b1c, hbuf);
  readout2<<<NB, 64, 0, stream>>>(hbuf, W2c, b2c, d_out, flag);
}

// Round 7
// 1704.807 us; speedup vs baseline: 4.4203x; 1.0507x over previous
//
#include <hip/hip_runtime.h>
#include <cstdint>
#include <cstddef>

typedef unsigned short u16;
typedef __bf16 bf16x8 __attribute__((ext_vector_type(8)));
typedef float f32x4 __attribute__((ext_vector_type(4)));
typedef unsigned short u16x8 __attribute__((ext_vector_type(8)));

#define NB   256
#define MAXN 128
#define MAXE 256
#define MAXC 64
#define HD   256
#define NLAYER 4
#define PN 131072
#define PE 98304
#define QE 131072
#define QC 65536
#define MN (NB*MAXN)   /* 32768 node rows  */
#define ME (NB*MAXE)   /* 65536 edge rows  */
#define MC (NB*MAXC)   /* 16384 cell rows  */

// CSR segment bases in the concatenated histogram/offset arrays
#define SEG_N  0
#define SEG_E  (MN)
#define SEG_EB (MN + ME)
#define SEG_CB (MN + 2*ME)
#define HTOT   (MN + 2*ME + MC)      /* 229376, divisible by 1024 */
#define UPTOT  (PN + PE)             /* csrBd global-index base   */

__device__ __forceinline__ float bf2f(u16 u){
  union{unsigned int i; float f;} x; x.i = ((unsigned int)u) << 16; return x.f;
}
__device__ __forceinline__ u16 f2bf(float f){
  union{float f; unsigned int i;} x; x.f = f;
  unsigned int r = x.i + 0x7fffu + ((x.i >> 16) & 1u);
  return (u16)(r >> 16);
}
__device__ __forceinline__ f32x4 MFMA(bf16x8 a, bf16x8 b, f32x4 c){
  return __builtin_amdgcn_mfma_f32_16x16x32_bf16(a, b, c, 0, 0, 0);
}
// async global->LDS, 16B per lane; lds base wave-uniform (lane*16 implicit)
__device__ __forceinline__ void gl_lds16(const u16* g, u16* l){
  __builtin_amdgcn_global_load_lds(
      (const __attribute__((address_space(1))) unsigned int*)g,
      (__attribute__((address_space(3))) unsigned int*)l, 16, 0, 0);
}

// ---------------- dtype sniff (bf16 vs f32 input buffers)
__global__ void detect_dtype(const u16* __restrict__ x, int* __restrict__ flag){
  if(threadIdx.x == 0 && blockIdx.x == 0){
    int cnt = 0;
    for(int i = 0; i < 64; i++){
      int e = (x[i] >> 7) & 0xFF;
      if(e >= 118 && e <= 136) cnt++;
    }
    *flag = (cnt >= 50) ? 1 : 0;   // 1 = bf16, 0 = f32
  }
}

// ---------------- dtype-aware convert to bf16
__global__ __launch_bounds__(256) void conv_bf(const void* __restrict__ src, u16* __restrict__ dst,
                                               long n, const int* __restrict__ flag){
  long i = ((long)blockIdx.x * 256 + threadIdx.x) * 8;
  if(i >= n) return;
  const int isbf = *flag;
  if(i + 8 <= n){
    if(isbf){
      *reinterpret_cast<u16x8*>(dst + i) = *reinterpret_cast<const u16x8*>((const u16*)src + i);
    }else{
      const float* s = (const float*)src + i;
      float4 a = *reinterpret_cast<const float4*>(s);
      float4 b = *reinterpret_cast<const float4*>(s + 4);
      u16x8 o;
      o[0]=f2bf(a.x); o[1]=f2bf(a.y); o[2]=f2bf(a.z); o[3]=f2bf(a.w);
      o[4]=f2bf(b.x); o[5]=f2bf(b.y); o[6]=f2bf(b.z); o[7]=f2bf(b.w);
      *reinterpret_cast<u16x8*>(dst + i) = o;
    }
  }else{
    for(long e = i; e < n; e++)
      dst[e] = isbf ? ((const u16*)src)[e] : f2bf(((const float*)src)[e]);
  }
}

// ---------------- zero fill
__global__ __launch_bounds__(256) void zero_f4(float* __restrict__ p, long n4){
  long i = (long)blockIdx.x * blockDim.x + threadIdx.x;
  if(i >= n4) return;
  float4 z = {0.f, 0.f, 0.f, 0.f};
  *reinterpret_cast<float4*>(p + i * 4) = z;
}

// ---------------- dtype-aware weight transpose: src [K,N] -> bf16 dst [n*256+k]
__global__ void wt_transpose(const void* __restrict__ src, u16* __restrict__ dst,
                             const int* __restrict__ flag){
  __shared__ u16 t[16][17];
  int m = blockIdx.z;
  int n0 = blockIdx.x * 16, k0 = blockIdx.y * 16;
  size_t sidx = (size_t)m * 65536 + (size_t)(k0 + threadIdx.y) * 256 + n0 + threadIdx.x;
  u16 v = (*flag) ? ((const u16*)src)[sidx] : f2bf(((const float*)src)[sidx]);
  t[threadIdx.y][threadIdx.x] = v;
  __syncthreads();
  dst[(size_t)m * 65536 + (size_t)(n0 + threadIdx.y) * 256 + (k0 + threadIdx.x)] =
      t[threadIdx.x][threadIdx.y];
}

// ---------------- dedup boundary incidences (.set(1.0): idempotent)
__global__ void dedup_kernel(const int* __restrict__ bb, const int* __restrict__ bi,
                             const int* __restrict__ bj, unsigned int* __restrict__ mask,
                             unsigned char* __restrict__ valid, int Q, int maxI, int maxJ){
  int q = blockIdx.x * blockDim.x + threadIdx.x;
  if(q >= Q) return;
  int s = (bb[q] * maxI + bi[q]) * maxJ + bj[q];
  unsigned int bit = 1u << (s & 31);
  unsigned int old = atomicOr(&mask[s >> 5], bit);
  valid[q] = (old & bit) ? 0 : 1;
}

// ---------------- CSR build: histogram
__global__ __launch_bounds__(256) void hist_up(const int* __restrict__ pb, const int* __restrict__ pi,
                                               int maxI, int segBase, int* __restrict__ hist, int P){
  int p = blockIdx.x * 256 + threadIdx.x;
  if(p >= P) return;
  atomicAdd(&hist[segBase + pb[p] * maxI + pi[p]], 1);
}
__global__ __launch_bounds__(256) void hist_bd(const int* __restrict__ bb, const int* __restrict__ bi,
                                               const unsigned char* __restrict__ valid,
                                               int maxI, int segBase, int* __restrict__ hist, int Q){
  int q = blockIdx.x * 256 + threadIdx.x;
  if(q >= Q || !valid[q]) return;
  atomicAdd(&hist[segBase + bb[q] * maxI + bi[q]], 1);
}

// ---------------- 3-phase exclusive scan over HTOT ints (1024 elems / block)
__global__ __launch_bounds__(256) void scan1(const int* __restrict__ hist, int* __restrict__ bsum){
  __shared__ int s[256];
  int t = threadIdx.x;
  long base = (long)blockIdx.x * 1024 + t * 4;
  int4 v = *reinterpret_cast<const int4*>(hist + base);
  s[t] = v.x + v.y + v.z + v.w;
  __syncthreads();
  for(int st = 128; st > 0; st >>= 1){
    if(t < st) s[t] += s[t + st];
    __syncthreads();
  }
  if(t == 0) bsum[blockIdx.x] = s[0];
}
__global__ __launch_bounds__(256) void scan2(int* __restrict__ bsum, int nb){
  __shared__ int s[256];
  int t = threadIdx.x;
  int v = (t < nb) ? bsum[t] : 0;
  s[t] = v;
  __syncthreads();
  for(int st = 1; st < 256; st <<= 1){
    int u = (t >= st) ? s[t - st] : 0;
    __syncthreads();
    s[t] += u;
    __syncthreads();
  }
  if(t < nb) bsum[t] = s[t] - v;   // exclusive
}
__global__ __launch_bounds__(256) void scan3(const int* __restrict__ hist, const int* __restrict__ bsum,
                                             int* __restrict__ off, int* __restrict__ cur){
  __shared__ int s[256];
  int t = threadIdx.x;
  long base = (long)blockIdx.x * 1024 + t * 4;
  int4 v = *reinterpret_cast<const int4*>(hist + base);
  int sum = v.x + v.y + v.z + v.w;
  s[t] = sum;
  __syncthreads();
  for(int st = 1; st < 256; st <<= 1){
    int u = (t >= st) ? s[t - st] : 0;
    __syncthreads();
    s[t] += u;
    __syncthreads();
  }
  int excl = s[t] - sum + bsum[blockIdx.x];
  int4 o;
  o.x = excl; o.y = o.x + v.x; o.z = o.y + v.y; o.w = o.z + v.z;
  *reinterpret_cast<int4*>(off + base) = o;
  *reinterpret_cast<int4*>(cur + base) = o;
}

// ---------------- CSR build: fill payloads (csrUp: global pos; csrBd: pos - UPTOT)
__global__ __launch_bounds__(256) void fill_up(const int* __restrict__ pb, const int* __restrict__ pi,
    const int* __restrict__ pj, const int* __restrict__ pa, int maxI, int maxA, int segBase,
    int* __restrict__ cur, int2* __restrict__ csrUp, int P){
  int p = blockIdx.x * 256 + threadIdx.x;
  if(p >= P) return;
  int b = pb[p];
  int pos = atomicAdd(&cur[segBase + b * maxI + pi[p]], 1);
  int2 e; e.x = b * maxI + pj[p]; e.y = b * maxA + pa[p];
  csrUp[pos] = e;
}
__global__ __launch_bounds__(256) void fill_bd(const int* __restrict__ bb, const int* __restrict__ bi,
    const int* __restrict__ bj, const unsigned char* __restrict__ valid, int maxI, int maxJ,
    int segBase, int* __restrict__ cur, int* __restrict__ csrBd, int Q){
  int q = blockIdx.x * 256 + threadIdx.x;
  if(q >= Q || !valid[q]) return;
  int b = bb[q];
  int pos = atomicAdd(&cur[segBase + b * maxI + bi[q]], 1);
  csrBd[pos - UPTOT] = b * maxJ + bj[q];
}

// ---------------- gather: one wave per receiver row; bf16 ACC store; XCD swizzle
// (contiguous row/graph ranges per XCD so per-XCD L2 holds the source slice)
template<int HAS_UP, int HAS_BD>
__global__ __launch_bounds__(256) void gather_k(
    const u16* __restrict__ Y, const u16* __restrict__ Z, const u16* __restrict__ BD,
    const int2* __restrict__ csrUp, const int* __restrict__ csrBd,
    const int* __restrict__ off, const int* __restrict__ deg,
    int upBase, int bdBase, u16* __restrict__ ACC, int rowLo){
  const int nb = gridDim.x;
  int bx = blockIdx.x;
  if((nb & 7) == 0) bx = (bx & 7) * (nb >> 3) + (bx >> 3);   // XCD-contiguous ranges
  const int row = rowLo + bx * 4 + (threadIdx.x >> 6);
  const int lane = threadIdx.x & 63;
  const int c = lane * 4;
  float a0 = 0.f, a1 = 0.f, a2 = 0.f, a3 = 0.f;
  if(HAS_UP){
    int s = off[upBase + row];
    int d = deg[upBase + row];
    for(int k = 0; k < d; k++){
      int2 e = csrUp[s + k];
      const ushort4 y = *reinterpret_cast<const ushort4*>(Y + (size_t)e.x * 256 + c);
      const ushort4 z = *reinterpret_cast<const ushort4*>(Z + (size_t)e.y * 256 + c);
      a0 += fmaxf(bf2f(y.x) + bf2f(z.x), 0.f);
      a1 += fmaxf(bf2f(y.y) + bf2f(z.y), 0.f);
      a2 += fmaxf(bf2f(y.z) + bf2f(z.z), 0.f);
      a3 += fmaxf(bf2f(y.w) + bf2f(z.w), 0.f);
    }
  }
  if(HAS_BD){
    int s = off[bdBase + row] - UPTOT;
    int d = deg[bdBase + row];
    for(int k = 0; k < d; k++){
      int j = csrBd[s + k];
      const ushort4 x = *reinterpret_cast<const ushort4*>(BD + (size_t)j * 256 + c);
      a0 += bf2f(x.x); a1 += bf2f(x.y); a2 += bf2f(x.z); a3 += bf2f(x.w);
    }
  }
  ushort4 o; o.x = f2bf(a0); o.y = f2bf(a1); o.z = f2bf(a2); o.w = f2bf(a3);
  *reinterpret_cast<ushort4*>(ACC + (size_t)(row - rowLo) * 256 + c) = o;
}

// ---------------- LDS-staged bf16 MFMA GEMM. Block = 512 thr (8 waves),
// tile 128 rows x 256 cols (full N), K staged in BK=64 via global_load_lds.
// MODE 0: C = A@W.  MODE 2: C = relu(A@W + ACCbf + bias), C may alias A.
// MODE 3: C = A@W + A2@W2 (dual-A accumulate, used for the pooling gate).
template<int MODE>
__global__ __launch_bounds__(512) void gemm_b(const u16* A, const u16* __restrict__ WT,
                                              u16* C, const u16* __restrict__ ACC,
                                              const u16* __restrict__ bias,
                                              const u16* A2, const u16* __restrict__ WT2){
  __shared__ u16 lA[128 * 64];   // [row][k]
  __shared__ u16 lB[256 * 64];   // [n][k]
  const int t = threadIdx.x;
  const int lane = t & 63, wv = t >> 6;
  const int wm = wv >> 2, wn = wv & 3;        // 2 x 4 wave grid, each 64x64
  const int r = lane & 15, q = lane >> 4;
  const size_t m0 = (size_t)blockIdx.x * 128;
  const int lrow = lane >> 3, lchk = lane & 7;

  f32x4 acc[4][4];
#pragma unroll
  for(int i = 0; i < 4; i++)
#pragma unroll
    for(int j = 0; j < 4; j++) acc[i][j] = {0.f, 0.f, 0.f, 0.f};

  const int nsrc = (MODE == 3) ? 2 : 1;
  for(int s = 0; s < nsrc; s++){
    const u16* Ap = s ? A2 : A;
    const u16* Wp = s ? WT2 : WT;
#pragma unroll
    for(int k0 = 0; k0 < 256; k0 += 64){
#pragma unroll
      for(int i = 0; i < 2; i++){
        const int row = i * 64 + wv * 8 + lrow;
        gl_lds16(Ap + (m0 + row) * 256 + k0 + lchk * 8, lA + (i * 64 + wv * 8) * 64);
      }
#pragma unroll
      for(int j = 0; j < 4; j++){
        const int n = j * 64 + wv * 8 + lrow;
        gl_lds16(Wp + (size_t)n * 256 + k0 + lchk * 8, lB + (j * 64 + wv * 8) * 64);
      }
      __syncthreads();
#pragma unroll
      for(int ks = 0; ks < 2; ks++){
        bf16x8 af[4], bf[4];
#pragma unroll
        for(int i = 0; i < 4; i++)
          af[i] = *reinterpret_cast<const bf16x8*>(lA + (wm * 64 + i * 16 + r) * 64 + ks * 32 + q * 8);
#pragma unroll
        for(int j = 0; j < 4; j++)
          bf[j] = *reinterpret_cast<const bf16x8*>(lB + (wn * 64 + j * 16 + r) * 64 + ks * 32 + q * 8);
#pragma unroll
        for(int i = 0; i < 4; i++)
#pragma unroll
          for(int j = 0; j < 4; j++) acc[i][j] = MFMA(af[i], bf[j], acc[i][j]);
      }
      __syncthreads();
    }
  }

  // epilogue: C/D layout col = lane&15, row = (lane>>4)*4 + reg
#pragma unroll
  for(int i = 0; i < 4; i++){
    const size_t row0 = m0 + wm * 64 + i * 16 + q * 4;
#pragma unroll
    for(int j = 0; j < 4; j++){
      const int col = wn * 64 + j * 16 + r;
#pragma unroll
      for(int reg = 0; reg < 4; reg++){
        const size_t idx = (row0 + reg) * 256 + col;
        float x = acc[i][j][reg];
        if(MODE == 2) x = fmaxf(x + bf2f(ACC[idx]) + bf2f(bias[col]), 0.f);
        C[idx] = f2bf(x);
      }
    }
  }
}

// ---------------- pooled[b,h] += sum_r sigmoid(G+bp)[r,h] * X[r,h]
__global__ __launch_bounds__(256) void pool_reduce(const u16* __restrict__ G, const u16* __restrict__ bpv,
    const u16* __restrict__ X, float* __restrict__ pooled, int maxR, int rowsPerBlk){
  int b = blockIdx.x, h = threadIdx.x;
  int r0 = blockIdx.y * rowsPerBlk;
  float bias = bf2f(bpv[h]);
  float acc = 0.f;
  for(int r = r0; r < r0 + rowsPerBlk; r++){
    size_t o = ((size_t)b * maxR + r) * 256 + h;
    float t = bf2f(G[o]) + bias;
    float w = 1.f / (1.f + __expf(-t));
    acc += w * bf2f(X[o]);
  }
  atomicAdd(&pooled[b * 256 + h], acc);
}

// ---------------- h[b,o] = sum_i relu(pooled_i[b,:] @ W1[i] + b1[i])
__global__ __launch_bounds__(512) void readout1(const float* __restrict__ pooled, const u16* __restrict__ W1,
                                                const u16* __restrict__ b1, float* __restrict__ hbuf){
  __shared__ float p[3][256];
  int b = blockIdx.x, o = threadIdx.x;
  if(o < 256){
    p[0][o] = pooled[(size_t)b * 256 + o];
    p[1][o] = pooled[(size_t)NB * 256 + (size_t)b * 256 + o];
    p[2][o] = pooled[(size_t)2 * NB * 256 + (size_t)b * 256 + o];
  }
  __syncthreads();
  float s = 0.f;
#pragma unroll
  for(int i = 0; i < 3; i++){
    float a = bf2f(b1[i * 512 + o]);
    for(int k = 0; k < 256; k++) a += p[i][k] * bf2f(W1[(size_t)(i * 256 + k) * 512 + o]);
    s += fmaxf(a, 0.f);
  }
  hbuf[(size_t)b * 512 + o] = s;
}

// ---------------- out = h @ W2 + b2 (dtype-matched store)
__global__ __launch_bounds__(64) void readout2(const float* __restrict__ hbuf, const u16* __restrict__ W2,
                                               const u16* __restrict__ b2, void* __restrict__ out,
                                               const int* __restrict__ flag){
  int b = blockIdx.x, o = threadIdx.x;
  if(o >= 10) return;
  float a = bf2f(b2[o]);
  for(int k = 0; k < 512; k++) a += hbuf[(size_t)b * 512 + k] * bf2f(W2[k * 10 + o]);
  if(*flag) ((u16*)out)[b * 10 + o] = f2bf(a);
  else      ((float*)out)[b * 10 + o] = a;
}

extern "C" void kernel_launch(void* const* d_in, const int* in_sizes, int n_in,
                              void* d_out, int out_size, void* d_ws, size_t ws_size,
                              hipStream_t stream){
  const void* x_n = d_in[0];
  const void* x_e = d_in[1];
  const void* x_c = d_in[2];
  const int* n_up_b = (const int*)d_in[3];
  const int* n_up_i = (const int*)d_in[4];
  const int* n_up_j = (const int*)d_in[5];
  const int* n_up_e = (const int*)d_in[6];
  const int* e_up_b = (const int*)d_in[7];
  const int* e_up_i = (const int*)d_in[8];
  const int* e_up_j = (const int*)d_in[9];
  const int* e_up_c = (const int*)d_in[10];
  const int* eb_b = (const int*)d_in[11];
  const int* eb_i = (const int*)d_in[12];
  const int* eb_j = (const int*)d_in[13];
  const int* cb_b = (const int*)d_in[14];
  const int* cb_i = (const int*)d_in[15];
  const int* cb_j = (const int*)d_in[16];

  // ---- workspace carve-up (~141 MiB, proven footprint)
  char* base = (char*)d_ws; size_t off0 = 0;
  auto alloc = [&](size_t n)->char*{ char* p = base + off0; off0 = (off0 + n + 255) & ~(size_t)255; return p; };
  u16* xn = (u16*)alloc((size_t)MN * HD * 2);
  u16* xe = (u16*)alloc((size_t)ME * HD * 2);
  u16* xc = (u16*)alloc((size_t)MC * HD * 2);
  u16* BIG1 = (u16*)alloc((size_t)ME * HD * 2);      // Ze/BDe/Ye/G staging
  u16* SMa  = (u16*)alloc((size_t)MN * HD * 2);      // Yn then Zc; pool: ref scratch
  u16* SMb  = (u16*)alloc((size_t)MN * HD * 2);      // BDn
  u16* ACC  = (u16*)alloc((size_t)16384 * HD * 4);   // 16 MiB region; bf16 chunks <= ME/2 rows
  u16* wt = (u16*)alloc((size_t)38 * 65536 * 2);
  unsigned int* mask_e = (unsigned int*)alloc((size_t)NB * MAXE * MAXN / 8);  // dead after dedup -> params
  unsigned int* mask_c = (unsigned int*)alloc((size_t)NB * MAXC * MAXE / 8);
  unsigned char* valid_e = (unsigned char*)alloc(QE);
  unsigned char* valid_c = (unsigned char*)alloc(QC);
  float* pooled = (float*)alloc((size_t)3 * NB * HD * 4);   // also aliased as scan cursor
  float* hbuf   = (float*)alloc((size_t)NB * 512 * 4);
  int* flag     = (int*)alloc(256);
  int2* csrUp   = (int2*)alloc((size_t)UPTOT * 8);
  int* csrBd    = (int*)alloc((size_t)(QE + QC) * 4);
  int* hist     = (int*)alloc((size_t)HTOT * 4);
  int* offA     = (int*)alloc((size_t)HTOT * 4);
  int* bsum     = (int*)alloc(1024);
  int* cur      = (int*)pooled;   // scan cursor; pooled dead until pooling

  u16* wtSelf = wt;
  u16* wtUpx  = wt + (size_t)12 * 65536;
  u16* wtUpa  = wt + (size_t)20 * 65536;
  u16* wtB    = wt + (size_t)28 * 65536;
  u16* wtP    = wt + (size_t)36 * 65536;
  u16* wtPref = wt + (size_t)37 * 65536;

  // small converted params in mask_e's 1 MiB (dead after dedup)
  u16* W1c = (u16*)mask_e;
  u16* b1c = W1c + 393216;
  u16* W2c = b1c + 1536;
  u16* b2c = W2c + 5120;
  u16* bsc = b2c + 16;
  u16* bpc = bsc + 3072;

  auto convN = [&](const void* s, u16* d, long n){
    long blk = (n + 8*256 - 1) / (8*256);
    conv_bf<<<(int)blk, 256, 0, stream>>>(s, d, n, flag);
  };

  // ---- prologue
  detect_dtype<<<1, 64, 0, stream>>>((const u16*)x_n, flag);
  zero_f4<<<(65536 + 255)/256, 256, 0, stream>>>((float*)mask_e, 65536);
  zero_f4<<<(32768 + 255)/256, 256, 0, stream>>>((float*)mask_c, 32768);
  dedup_kernel<<<QE/256, 256, 0, stream>>>(eb_b, eb_i, eb_j, mask_e, valid_e, QE, MAXE, MAXN);
  dedup_kernel<<<QC/256, 256, 0, stream>>>(cb_b, cb_i, cb_j, mask_c, valid_c, QC, MAXC, MAXE);

  wt_transpose<<<dim3(16,16,12), dim3(16,16), 0, stream>>>(d_in[17], wtSelf, flag);
  wt_transpose<<<dim3(16,16,8),  dim3(16,16), 0, stream>>>(d_in[19], wtUpx,  flag);
  wt_transpose<<<dim3(16,16,8),  dim3(16,16), 0, stream>>>(d_in[20], wtUpa,  flag);
  wt_transpose<<<dim3(16,16,8),  dim3(16,16), 0, stream>>>(d_in[21], wtB,    flag);
  wt_transpose<<<dim3(16,16,1),  dim3(16,16), 0, stream>>>(d_in[22], wtP,    flag);
  wt_transpose<<<dim3(16,16,1),  dim3(16,16), 0, stream>>>(d_in[23], wtPref, flag);
  convN(x_n, xn, (long)MN * HD);
  convN(x_e, xe, (long)ME * HD);
  convN(x_c, xc, (long)MC * HD);
  convN(d_in[18], bsc, 3072);
  convN(d_in[24], bpc, 256);
  convN(d_in[25], W1c, 393216);
  convN(d_in[26], b1c, 1536);
  convN(d_in[27], W2c, 5120);
  convN(d_in[28], b2c, 10);

  // ---- CSR build (histogram -> scan -> fill)
  zero_f4<<<(HTOT/4 + 255)/256, 256, 0, stream>>>((float*)hist, HTOT/4);
  hist_up<<<PN/256, 256, 0, stream>>>(n_up_b, n_up_i, MAXN, SEG_N,  hist, PN);
  hist_up<<<PE/256, 256, 0, stream>>>(e_up_b, e_up_i, MAXE, SEG_E,  hist, PE);
  hist_bd<<<QE/256, 256, 0, stream>>>(eb_b, eb_i, valid_e, MAXE, SEG_EB, hist, QE);
  hist_bd<<<QC/256, 256, 0, stream>>>(cb_b, cb_i, valid_c, MAXC, SEG_CB, hist, QC);
  scan1<<<HTOT/1024, 256, 0, stream>>>(hist, bsum);
  scan2<<<1, 256, 0, stream>>>(bsum, HTOT/1024);
  scan3<<<HTOT/1024, 256, 0, stream>>>(hist, bsum, offA, cur);
  fill_up<<<PN/256, 256, 0, stream>>>(n_up_b, n_up_i, n_up_j, n_up_e, MAXN, MAXE, SEG_N, cur, csrUp, PN);
  fill_up<<<PE/256, 256, 0, stream>>>(e_up_b, e_up_i, e_up_j, e_up_c, MAXE, MAXC, SEG_E, cur, csrUp, PE);
  fill_bd<<<QE/256, 256, 0, stream>>>(eb_b, eb_i, eb_j, valid_e, MAXE, MAXN, SEG_EB, cur, csrBd, QE);
  fill_bd<<<QC/256, 256, 0, stream>>>(cb_b, cb_i, cb_j, valid_c, MAXC, MAXE, SEG_CB, cur, csrBd, QC);

  // ---- layers
  for(int l = 0; l < NLAYER; l++){
    const u16* Wupx0 = wtUpx + (size_t)(l*2+0) * 65536;
    const u16* Wupx1 = wtUpx + (size_t)(l*2+1) * 65536;
    const u16* Wupa0 = wtUpa + (size_t)(l*2+0) * 65536;
    const u16* Wupa1 = wtUpa + (size_t)(l*2+1) * 65536;
    const u16* Wb0   = wtB   + (size_t)(l*2+0) * 65536;
    const u16* Wb1   = wtB   + (size_t)(l*2+1) * 65536;
    const u16* Ws0   = wtSelf + (size_t)(l*3+0) * 65536;
    const u16* Ws1   = wtSelf + (size_t)(l*3+1) * 65536;
    const u16* Ws2   = wtSelf + (size_t)(l*3+2) * 65536;
    const u16* bs0 = bsc + (size_t)(l*3+0) * HD;
    const u16* bs1 = bsc + (size_t)(l*3+1) * HD;
    const u16* bs2 = bsc + (size_t)(l*3+2) * HD;

    // nodes: Yn (SMa), Ze (BIG1), BDn (SMb, held) from OLD features; 2 row-halves
    gemm_b<0><<<MN/128, 512, 0, stream>>>(xn, Wupx0, SMa, nullptr, nullptr, nullptr, nullptr);
    gemm_b<0><<<ME/128, 512, 0, stream>>>(xe, Wupa0, BIG1, nullptr, nullptr, nullptr, nullptr);
    gemm_b<0><<<MN/128, 512, 0, stream>>>(xn, Wb0, SMb, nullptr, nullptr, nullptr, nullptr);
    for(int h = 0; h < 2; h++){
      int lo = h * (MN/2);
      gather_k<1,0><<<(MN/2)/4, 256, 0, stream>>>(SMa, BIG1, nullptr, csrUp, csrBd,
                                                  offA, hist, SEG_N, 0, ACC, lo);
      gemm_b<2><<<(MN/2)/128, 512, 0, stream>>>(xn + (size_t)lo * HD, Ws0,
                                                xn + (size_t)lo * HD, ACC, bs0, nullptr, nullptr);
    }

    // cells: Zc (SMa, held for edges), BDe (BIG1); gather + fused self
    gemm_b<0><<<MC/128, 512, 0, stream>>>(xc, Wupa1, SMa, nullptr, nullptr, nullptr, nullptr);
    gemm_b<0><<<ME/128, 512, 0, stream>>>(xe, Wb1, BIG1, nullptr, nullptr, nullptr, nullptr);
    gather_k<0,1><<<MC/4, 256, 0, stream>>>(nullptr, nullptr, BIG1, csrUp, csrBd,
                                            offA, hist, 0, SEG_CB, ACC, 0);
    gemm_b<2><<<MC/128, 512, 0, stream>>>(xc, Ws2, xc, ACC, bs2, nullptr, nullptr);

    // edges: Ye (BIG1) from OLD xe; 2 row-halves (bf16 ACC fits ME/2)
    gemm_b<0><<<ME/128, 512, 0, stream>>>(xe, Wupx1, BIG1, nullptr, nullptr, nullptr, nullptr);
    for(int h = 0; h < 2; h++){
      int lo = h * (ME/2);
      gather_k<1,1><<<(ME/2)/4, 256, 0, stream>>>(BIG1, SMa, SMb, csrUp, csrBd,
                                                  offA, hist, SEG_E, SEG_EB, ACC, lo);
      gemm_b<2><<<(ME/2)/128, 512, 0, stream>>>(xe + (size_t)lo * HD, Ws1,
                                                xe + (size_t)lo * HD, ACC, bs1, nullptr, nullptr);
    }
  }

  // ---- gated pooling: G = x@Wp + ref@Wp_ref in ONE dual-A GEMM per dim
  u16* REF = SMa;
  {
    long np4 = (long)3 * NB * HD / 4;
    zero_f4<<<(int)((np4 + 255)/256), 256, 0, stream>>>(pooled, np4);
  }
  convN(x_n, REF, (long)MN * HD);
  gemm_b<3><<<MN/128, 512, 0, stream>>>(xn, wtP, BIG1, nullptr, nullptr, REF, wtPref);
  pool_reduce<<<dim3(NB,2), 256, 0, stream>>>(BIG1, bpc, xn, pooled, MAXN, MAXN/2);

  convN(x_e, REF, (long)ME * HD);
  gemm_b<3><<<ME/128, 512, 0, stream>>>(xe, wtP, BIG1, nullptr, nullptr, REF, wtPref);
  pool_reduce<<<dim3(NB,4), 256, 0, stream>>>(BIG1, bpc, xe, pooled + (size_t)NB*HD, MAXE, MAXE/4);

  convN(x_c, REF, (long)MC * HD);
  gemm_b<3><<<MC/128, 512, 0, stream>>>(xc, wtP, BIG1, nullptr, nullptr, REF, wtPref);
  pool_reduce<<<dim3(NB,1), 256, 0, stream>>>(BIG1, bpc, xc, pooled + (size_t)2*NB*HD, MAXC, MAXC);

  // ---- readout
  readout1<<<NB, 512, 0, stream>>>(pooled, W1c, b1c, hbuf);
  readout2<<<NB, 64, 0, stream>>>(hbuf, W2c, b2c, d_out, flag);
}